// Round 10
// baseline (4281.581 us; speedup 1.0000x reference)
//
#include <hip/hip_runtime.h>
#include <hip/hip_cooperative_groups.h>

namespace cg = cooperative_groups;

// GCN 2-layer + head.
// R10: slice-phased cooperative aggregation. src-space cut into 8 slices of
// 3.2 MB; persistent grid (2048 blocks) iterates slices with grid.sync()
// between phases so every XCD's L2 holds the current slice entirely.
// CSR neighbor lists partitioned by slice in csrbuild (sliceptr[N*8+1]).
// Fallback to non-cooperative kernels if cooperative launch is refused.
// bucket word = (src<<7) | (dst&127), src < 2^17 fits 24 bits.

#define HID 64
#define INC 11
#define BINSH 7
#define BINW 128
#define MAXNB 800      // >= ceil(100000/128)=782
#define ECHUNK 8192
#define SCAN_CHUNK 1024
#define STAGE_MAX 6144
#define NSLICE 8
#define NBLK 2048      // cooperative grid: 8 blocks/CU x 256 CU
#define MAXROWS 13     // ceil(100000 / (2048*4 waves))

// ---- per-chunk histogram of dst bins, stored transposed histT[b*C+c] ----
__global__ void k_hist(const int* __restrict__ dst, int E, int C, int NB,
                       int* __restrict__ histT) {
    __shared__ int h[MAXNB];
    int c = blockIdx.x, t = threadIdx.x;
    for (int i = t; i < NB; i += 256) h[i] = 0;
    __syncthreads();
    int base = c * ECHUNK;
    int end = min(base + ECHUNK, E);
    int n4 = (end - base) >> 2;
    const int4* d4 = (const int4*)(dst + base);
    for (int i = t; i < n4; i += 256) {
        int4 d = d4[i];
        atomicAdd(&h[d.x >> BINSH], 1);
        atomicAdd(&h[d.y >> BINSH], 1);
        atomicAdd(&h[d.z >> BINSH], 1);
        atomicAdd(&h[d.w >> BINSH], 1);
    }
    __syncthreads();
    for (int b = t; b < NB; b += 256)
        histT[(size_t)b * C + c] = h[b];
}

// ---- generic 3-kernel exclusive scan (in-place safe), L <= 512*SCAN_CHUNK ----
__global__ void k_scan1(const int* __restrict__ in, int L,
                        int* __restrict__ part, int* __restrict__ blocksums) {
    __shared__ int lds[SCAN_CHUNK];
    __shared__ int tsum[256];
    int b = blockIdx.x, t = threadIdx.x;
    int base = b * SCAN_CHUNK;
    for (int i = t; i < SCAN_CHUNK; i += 256)
        lds[i] = (base + i < L) ? in[base + i] : 0;
    __syncthreads();
    int a0 = lds[t*4], a1 = lds[t*4+1], a2 = lds[t*4+2], a3 = lds[t*4+3];
    int ts = a0 + a1 + a2 + a3;
    tsum[t] = ts;
    __syncthreads();
    for (int off = 1; off < 256; off <<= 1) {
        int v = (t >= off) ? tsum[t - off] : 0;
        __syncthreads();
        tsum[t] += v;
        __syncthreads();
    }
    int excl = tsum[t] - ts;
    int i0 = base + t*4;
    if (i0     < L) part[i0]     = excl;
    if (i0 + 1 < L) part[i0 + 1] = excl + a0;
    if (i0 + 2 < L) part[i0 + 2] = excl + a0 + a1;
    if (i0 + 3 < L) part[i0 + 3] = excl + a0 + a1 + a2;
    if (t == 255) blocksums[b] = tsum[255];
}

__global__ void k_scan2(const int* __restrict__ blocksums, int nb, int* __restrict__ blockoff) {
    __shared__ int s[512];
    int t = threadIdx.x;    // 512 threads
    s[t] = (t < nb) ? blocksums[t] : 0;
    __syncthreads();
    int mine = s[t];
    for (int off = 1; off < 512; off <<= 1) {
        int v = (t >= off) ? s[t - off] : 0;
        __syncthreads();
        s[t] += v;
        __syncthreads();
    }
    blockoff[t] = s[t] - mine;   // exclusive
}

__global__ void k_scan3f(int* __restrict__ part, const int* __restrict__ blockoff, int L) {
    int i = blockIdx.x * blockDim.x + threadIdx.x;
    if (i < L) part[i] += blockoff[i / SCAN_CHUNK];
}

// ---- scatter edges into bin-grouped bucket; rank via LDS atomic, 8 chains ----
__global__ void k_scatterbin(const int* __restrict__ src, const int* __restrict__ dst,
                             int E, int C, int NB, const int* __restrict__ scanT,
                             int* __restrict__ bucket) {
    __shared__ int cur[MAXNB];
    int c = blockIdx.x, t = threadIdx.x;
    for (int b = t; b < NB; b += 256) cur[b] = scanT[(size_t)b * C + c];
    __syncthreads();
    int base = c * ECHUNK;
    int end = min(base + ECHUNK, E);
    int n4 = (end - base) >> 2;
    const int4* d4 = (const int4*)(dst + base);
    const int4* s4 = (const int4*)(src + base);
    for (int i = t; i < n4; i += 512) {
        int4 da = d4[i], sa = s4[i];
        bool hb = (i + 256) < n4;
        int4 db, sb;
        if (hb) { db = d4[i + 256]; sb = s4[i + 256]; }
        int r0 = atomicAdd(&cur[da.x >> BINSH], 1);
        int r1 = atomicAdd(&cur[da.y >> BINSH], 1);
        int r2 = atomicAdd(&cur[da.z >> BINSH], 1);
        int r3 = atomicAdd(&cur[da.w >> BINSH], 1);
        int r4 = 0, r5 = 0, r6 = 0, r7 = 0;
        if (hb) {
            r4 = atomicAdd(&cur[db.x >> BINSH], 1);
            r5 = atomicAdd(&cur[db.y >> BINSH], 1);
            r6 = atomicAdd(&cur[db.z >> BINSH], 1);
            r7 = atomicAdd(&cur[db.w >> BINSH], 1);
        }
        bucket[r0] = (sa.x << BINSH) | (da.x & (BINW - 1));
        bucket[r1] = (sa.y << BINSH) | (da.y & (BINW - 1));
        bucket[r2] = (sa.z << BINSH) | (da.z & (BINW - 1));
        bucket[r3] = (sa.w << BINSH) | (da.w & (BINW - 1));
        if (hb) {
            bucket[r4] = (sb.x << BINSH) | (db.x & (BINW - 1));
            bucket[r5] = (sb.y << BINSH) | (db.y & (BINW - 1));
            bucket[r6] = (sb.z << BINSH) | (db.z & (BINW - 1));
            bucket[r7] = (sb.w << BINSH) | (db.w & (BINW - 1));
        }
    }
}

// ---- per-bin CSR finalize with slice partitioning.
//      cnt2[dl*8+sl] histogram -> in-LDS scan of 1024 -> sliceptr, dis,
//      rank-scatter via LDS staging -> coalesced csr write. ----
__global__ void k_csrbuild(const int* __restrict__ scanT, int C, int NB, int E,
                           const int* __restrict__ bucket, int* __restrict__ csr,
                           int* __restrict__ sliceptr, float* __restrict__ dis,
                           int N, int SLICEW) {
    __shared__ int cnt2[BINW * NSLICE];   // 4 KB: counts -> exclusive scan (in place)
    __shared__ int tsum[256];
    __shared__ int stage[STAGE_MAX];      // 24 KB
    int b = blockIdx.x, t = threadIdx.x;
    int s = scanT[(size_t)b * C];
    int e = (b + 1 < NB) ? scanT[(size_t)(b + 1) * C] : E;
    int len = e - s;
    for (int i = t; i < BINW * NSLICE; i += 256) cnt2[i] = 0;
    __syncthreads();
    for (int p = s + t; p < e; p += 256) {
        int w = bucket[p];
        int sl = (w >> BINSH) / SLICEW;
        atomicAdd(&cnt2[(w & (BINW - 1)) * NSLICE + sl], 1);
    }
    __syncthreads();
    // dis from per-row totals (before scan overwrites cnt2)
    if (t < BINW) {
        int n = b * BINW + t;
        if (n < N) {
            int d = 0;
            #pragma unroll
            for (int j = 0; j < NSLICE; ++j) d += cnt2[t * NSLICE + j];
            dis[n] = rsqrtf((float)(d + 1));
        }
    }
    __syncthreads();
    // in-place exclusive scan of cnt2[0..1023]
    int a0 = cnt2[t*4], a1 = cnt2[t*4+1], a2 = cnt2[t*4+2], a3 = cnt2[t*4+3];
    int ts = a0 + a1 + a2 + a3;
    tsum[t] = ts;
    __syncthreads();
    for (int off = 1; off < 256; off <<= 1) {
        int v = (t >= off) ? tsum[t - off] : 0;
        __syncthreads();
        tsum[t] += v;
        __syncthreads();
    }
    int excl = tsum[t] - ts;
    cnt2[t*4]   = excl;
    cnt2[t*4+1] = excl + a0;
    cnt2[t*4+2] = excl + a0 + a1;
    cnt2[t*4+3] = excl + a0 + a1 + a2;
    __syncthreads();
    // write sliceptr: global index gi = b*1024 + j  (= n*8 + sl)
    #pragma unroll
    for (int u = 0; u < 4; ++u) {
        int j = t * 4 + u;
        size_t gi = (size_t)b * (BINW * NSLICE) + j;
        if (gi <= (size_t)N * NSLICE) sliceptr[gi] = s + cnt2[j];
    }
    // rank-scatter into staging, then coalesced csr write
    if (len <= STAGE_MAX) {
        for (int p = s + t; p < e; p += 256) {
            int w = bucket[p];
            int srcv = w >> BINSH;
            int sl = srcv / SLICEW;
            int r = atomicAdd(&cnt2[(w & (BINW - 1)) * NSLICE + sl], 1);
            stage[r] = srcv;
        }
        __syncthreads();
        for (int i = t; i < len; i += 256) csr[s + i] = stage[i];
    } else {
        for (int p = s + t; p < e; p += 256) {
            int w = bucket[p];
            int srcv = w >> BINSH;
            int sl = srcv / SLICEW;
            int r = atomicAdd(&cnt2[(w & (BINW - 1)) * NSLICE + sl], 1);
            csr[s + r] = srcv;
        }
    }
}

// ---- g1[N,64] = dis[row] * (x[N,11] @ W1[11,64]) ----
__global__ void k_xw1(const float* __restrict__ x, const float* __restrict__ W1,
                      const float* __restrict__ dis, float* __restrict__ g, int N) {
    __shared__ float Ws[INC * HID];
    int t = threadIdx.x;
    for (int i = t; i < INC * HID; i += blockDim.x) Ws[i] = W1[i];
    __syncthreads();
    int c = t & 63;
    for (int row = blockIdx.x * 4 + (t >> 6); row < N; row += gridDim.x * 4) {
        float acc = 0.f;
        #pragma unroll
        for (int k = 0; k < INC; ++k) acc += x[row * INC + k] * Ws[k * HID + c];
        g[row * HID + c] = dis[row] * acc;
    }
}

// ---- gather one (row, slice) segment ----
__device__ __forceinline__ float seg_gather(const int* __restrict__ csr,
                                            const float* __restrict__ g,
                                            int p0, int p1, int lane, float a) {
    for (int p = p0; p < p1; p += 64) {
        int idx = (p + lane < p1) ? csr[p + lane] : 0;
        int cnt = min(64, p1 - p);
        int j = 0;
        for (; j + 3 < cnt; j += 4) {
            int s0 = __shfl(idx, j);
            int s1 = __shfl(idx, j + 1);
            int s2 = __shfl(idx, j + 2);
            int s3 = __shfl(idx, j + 3);
            float v0 = g[(size_t)s0 * HID + lane];
            float v1 = g[(size_t)s1 * HID + lane];
            float v2 = g[(size_t)s2 * HID + lane];
            float v3 = g[(size_t)s3 * HID + lane];
            a += v0; a += v1; a += v2; a += v3;
        }
        for (; j < cnt; ++j)
            a += g[(size_t)__shfl(idx, j) * HID + lane];
    }
    return a;
}

// ---- cooperative slice-phased layer-1 agg + fused xw2 ----
__global__ __launch_bounds__(256, 8)
void k_agg1c(const int* __restrict__ sliceptr, const int* __restrict__ csr,
             const float* __restrict__ g, const float* __restrict__ dis,
             const float* __restrict__ b1, const float* __restrict__ W2,
             float* __restrict__ g2, int N) {
    __shared__ float W2s[HID * HID];   // 16 KB
    __shared__ float arow[4][HID];
    cg::grid_group grid = cg::this_grid();
    int t = threadIdx.x;
    for (int i = t; i < HID * HID; i += 256) W2s[i] = W2[i];
    int lane = t & 63, wv = t >> 6;
    int wave = blockIdx.x * 4 + wv;
    const int nw = gridDim.x * 4;
    float acc[MAXROWS];
    #pragma unroll
    for (int i = 0; i < MAXROWS; ++i) acc[i] = 0.f;
    for (int sl = 0; sl < NSLICE; ++sl) {
        #pragma unroll 1
        for (int ri = 0; ri < MAXROWS; ++ri) {
            int row = wave + ri * nw;
            if (row >= N) break;
            int p0 = sliceptr[(size_t)row * NSLICE + sl];
            int p1 = sliceptr[(size_t)row * NSLICE + sl + 1];
            acc[ri] = seg_gather(csr, g, p0, p1, lane, acc[ri]);
        }
        grid.sync();   // phase boundary: all waves advance to next slice together
    }
    // epilogue (grid.sync implies block barrier -> W2s ready)
    float bb = b1[lane];
    #pragma unroll 1
    for (int ri = 0; ri < MAXROWS; ++ri) {
        int row = wave + ri * nw;
        if (row >= N) break;
        float d = dis[row];
        float v = d * (acc[ri] + g[(size_t)row * HID + lane]) + bb;
        v = v > 0.f ? v : 0.f;
        arow[wv][lane] = v;          // wave-internal exchange
        float acc2 = 0.f;
        #pragma unroll
        for (int k = 0; k < HID; k += 4) {
            float a0 = arow[wv][k], a1 = arow[wv][k+1], a2 = arow[wv][k+2], a3 = arow[wv][k+3];
            acc2 += a0 * W2s[(k    ) * HID + lane];
            acc2 += a1 * W2s[(k + 1) * HID + lane];
            acc2 += a2 * W2s[(k + 2) * HID + lane];
            acc2 += a3 * W2s[(k + 3) * HID + lane];
        }
        g2[(size_t)row * HID + lane] = d * acc2;
    }
}

// ---- cooperative slice-phased layer-2 agg + fused head ----
__global__ __launch_bounds__(256, 8)
void k_agg2c(const int* __restrict__ sliceptr, const int* __restrict__ csr,
             const float* __restrict__ g, const float* __restrict__ dis,
             const float* __restrict__ b2, const float* __restrict__ Wl,
             const float* __restrict__ bl, float* __restrict__ out, int N) {
    cg::grid_group grid = cg::this_grid();
    int t = threadIdx.x;
    int lane = t & 63, wv = t >> 6;
    int wave = blockIdx.x * 4 + wv;
    const int nw = gridDim.x * 4;
    float acc[MAXROWS];
    #pragma unroll
    for (int i = 0; i < MAXROWS; ++i) acc[i] = 0.f;
    for (int sl = 0; sl < NSLICE; ++sl) {
        #pragma unroll 1
        for (int ri = 0; ri < MAXROWS; ++ri) {
            int row = wave + ri * nw;
            if (row >= N) break;
            int p0 = sliceptr[(size_t)row * NSLICE + sl];
            int p1 = sliceptr[(size_t)row * NSLICE + sl + 1];
            acc[ri] = seg_gather(csr, g, p0, p1, lane, acc[ri]);
        }
        grid.sync();
    }
    float bb = b2[lane];
    float wl = Wl[lane];
    #pragma unroll 1
    for (int ri = 0; ri < MAXROWS; ++ri) {
        int row = wave + ri * nw;
        if (row >= N) break;
        float v = dis[row] * (acc[ri] + g[(size_t)row * HID + lane]) + bb;
        v = v > 0.f ? v : 0.f;
        v *= wl;
        #pragma unroll
        for (int off = 32; off > 0; off >>= 1) v += __shfl_down(v, off);
        if (lane == 0) out[row] = v + bl[0];
    }
}

// ---- fallback (non-cooperative) wave-per-row kernels, read sliceptr ----
__device__ __forceinline__ float agg_row_fb(const int* __restrict__ sliceptr,
                                            const int* __restrict__ csr,
                                            const float* __restrict__ g,
                                            int row, int lane) {
    int s = sliceptr[(size_t)row * NSLICE];
    int e = sliceptr[(size_t)row * NSLICE + NSLICE];
    float acc = g[(size_t)row * HID + lane];
    return seg_gather(csr, g, s, e, lane, acc);
}

__global__ void k_agg1_fb(const int* __restrict__ sliceptr, const int* __restrict__ csr,
                          const float* __restrict__ g, const float* __restrict__ dis,
                          const float* __restrict__ b1, const float* __restrict__ W2,
                          float* __restrict__ g2, int N) {
    __shared__ float W2s[HID * HID];
    __shared__ float arow[4][HID];
    int t = threadIdx.x;
    for (int i = t; i < HID * HID; i += 256) W2s[i] = W2[i];
    __syncthreads();
    int lane = t & 63, wv = t >> 6;
    int row = (blockIdx.x * blockDim.x + t) >> 6;
    if (row >= N) return;
    float acc = agg_row_fb(sliceptr, csr, g, row, lane);
    float d = dis[row];
    float v = d * acc + b1[lane];
    v = v > 0.f ? v : 0.f;
    arow[wv][lane] = v;
    float acc2 = 0.f;
    #pragma unroll
    for (int k = 0; k < HID; k += 4) {
        float a0 = arow[wv][k], a1 = arow[wv][k+1], a2 = arow[wv][k+2], a3 = arow[wv][k+3];
        acc2 += a0 * W2s[(k    ) * HID + lane];
        acc2 += a1 * W2s[(k + 1) * HID + lane];
        acc2 += a2 * W2s[(k + 2) * HID + lane];
        acc2 += a3 * W2s[(k + 3) * HID + lane];
    }
    g2[(size_t)row * HID + lane] = d * acc2;
}

__global__ void k_agg2_fb(const int* __restrict__ sliceptr, const int* __restrict__ csr,
                          const float* __restrict__ g, const float* __restrict__ dis,
                          const float* __restrict__ b2, const float* __restrict__ Wl,
                          const float* __restrict__ bl, float* __restrict__ out, int N) {
    int lane = threadIdx.x & 63;
    int row = (blockIdx.x * blockDim.x + threadIdx.x) >> 6;
    if (row >= N) return;
    float acc = agg_row_fb(sliceptr, csr, g, row, lane);
    float v = dis[row] * acc + b2[lane];
    v = v > 0.f ? v : 0.f;
    v *= Wl[lane];
    #pragma unroll
    for (int off = 32; off > 0; off >>= 1) v += __shfl_down(v, off);
    if (lane == 0) out[row] = v + bl[0];
}

extern "C" void kernel_launch(void* const* d_in, const int* in_sizes, int n_in,
                              void* d_out, int out_size, void* d_ws, size_t ws_size,
                              hipStream_t stream) {
    const float* x  = (const float*)d_in[0];
    const int*   ei = (const int*)d_in[1];
    const float* W1 = (const float*)d_in[2];
    const float* b1 = (const float*)d_in[3];
    const float* W2 = (const float*)d_in[4];
    const float* b2 = (const float*)d_in[5];
    const float* Wl = (const float*)d_in[6];
    const float* bl = (const float*)d_in[7];
    float* out = (float*)d_out;

    int N = in_sizes[0] / INC;    // 100000
    int E = in_sizes[1] / 2;      // 3200000
    const int NB = (N + BINW - 1) / BINW;        // 782
    const int C  = (E + ECHUNK - 1) / ECHUNK;    // 391
    const int L  = NB * C;                        // 305762
    const int nScan = (L + SCAN_CHUNK - 1) / SCAN_CHUNK;  // 299 (<=512)
    int SLICEW = (N + NSLICE - 1) / NSLICE;       // 12500

    char* ws = (char*)d_ws;
    size_t off = 0;
    auto alloc = [&](size_t bytes) { void* p = ws + off; off += (bytes + 255) / 256 * 256; return p; };
    int*   histT    = (int*)alloc((size_t)L * 4);     // scanned in place
    int*   blocksums= (int*)alloc(512 * 4);
    int*   blockoff = (int*)alloc(512 * 4);
    int*   sliceptr = (int*)alloc(((size_t)N * NSLICE + NSLICE) * 4);  // 3.2 MB
    float* dis      = (float*)alloc((size_t)N * 4);
    int*   csr      = (int*)alloc((size_t)E * 4);
    float* bufG1    = (float*)alloc((size_t)N * HID * 4);
    float* bufG2    = (float*)alloc((size_t)N * HID * 4);
    // bucket (E ints) aliases bufG1: last read (k_csrbuild) precedes k_xw1's write.
    int* bucket = (int*)bufG1;

    const int TPB = 256;
    const int* esrc = ei;
    const int* edst = ei + E;
    const int waveBlocks = ((size_t)N * 64 + TPB - 1) / TPB;

    // CSR build — zero global atomics, slice-partitioned rows
    k_hist<<<C, TPB, 0, stream>>>(edst, E, C, NB, histT);
    k_scan1<<<nScan, TPB, 0, stream>>>(histT, L, histT, blocksums);
    k_scan2<<<1, 512, 0, stream>>>(blocksums, nScan, blockoff);
    k_scan3f<<<(L + TPB - 1) / TPB, TPB, 0, stream>>>(histT, blockoff, L);
    k_scatterbin<<<C, TPB, 0, stream>>>(esrc, edst, E, C, NB, histT, bucket);
    k_csrbuild<<<NB, TPB, 0, stream>>>(histT, C, NB, E, bucket, csr, sliceptr, dis, N, SLICEW);

    // layer 1 feature transform
    k_xw1<<<2048, TPB, 0, stream>>>(x, W1, dis, bufG1, N);

    // layer 1 aggregation (+ fused xw2): cooperative slice-phased, with fallback
    {
        void* args[] = { (void*)&sliceptr, (void*)&csr, (void*)&bufG1, (void*)&dis,
                         (void*)&b1, (void*)&W2, (void*)&bufG2, (void*)&N };
        hipError_t err = hipLaunchCooperativeKernel((const void*)k_agg1c,
                              dim3(NBLK), dim3(TPB), args, 0, stream);
        if (err != hipSuccess) {
            k_agg1_fb<<<waveBlocks, TPB, 0, stream>>>(sliceptr, csr, bufG1, dis, b1, W2, bufG2, N);
        }
    }

    // layer 2 aggregation (+ fused head): cooperative slice-phased, with fallback
    {
        void* args[] = { (void*)&sliceptr, (void*)&csr, (void*)&bufG2, (void*)&dis,
                         (void*)&b2, (void*)&Wl, (void*)&bl, (void*)&out, (void*)&N };
        hipError_t err = hipLaunchCooperativeKernel((const void*)k_agg2c,
                              dim3(NBLK), dim3(TPB), args, 0, stream);
        if (err != hipSuccess) {
            k_agg2_fb<<<waveBlocks, TPB, 0, stream>>>(sliceptr, csr, bufG2, dis, b2, Wl, bl, out, N);
        }
    }
}

// Round 11
// 272.482 us; speedup vs baseline: 15.7133x; 15.7133x over previous
//
#include <hip/hip_runtime.h>

// GCN 2-layer + head.
// R11: layer-1 aggregation moved to x-space (linearity: sum(dis_j x_j) @ W1),
//      gather table = xs[N][16] (dis*x, padded) = 6.4 MB (~L2-resident),
//      64 B/edge payload; epilogue applies W1 + self + b1 + relu + fused W2.
//      Layer-2 agg unchanged (no linear factorization through the ReLU).
//      Build: R9's atomic-free binned CSR. Cooperative phasing reverted (R10:
//      traffic dropped as predicted but grid.sync cost ~2 ms).
// bucket word = (src<<7) | (dst&127), src < 2^17 fits 24 bits.

#define HID 64
#define INC 11
#define XPAD 16
#define BINSH 7
#define BINW 128
#define MAXNB 800      // >= ceil(100000/128)=782
#define ECHUNK 8192
#define SCAN_CHUNK 1024
#define STAGE_MAX 6144

// ---- per-chunk histogram of dst bins, stored transposed histT[b*C+c] ----
__global__ void k_hist(const int* __restrict__ dst, int E, int C, int NB,
                       int* __restrict__ histT) {
    __shared__ int h[MAXNB];
    int c = blockIdx.x, t = threadIdx.x;
    for (int i = t; i < NB; i += 256) h[i] = 0;
    __syncthreads();
    int base = c * ECHUNK;
    int end = min(base + ECHUNK, E);
    int n4 = (end - base) >> 2;
    const int4* d4 = (const int4*)(dst + base);
    for (int i = t; i < n4; i += 256) {
        int4 d = d4[i];
        atomicAdd(&h[d.x >> BINSH], 1);
        atomicAdd(&h[d.y >> BINSH], 1);
        atomicAdd(&h[d.z >> BINSH], 1);
        atomicAdd(&h[d.w >> BINSH], 1);
    }
    __syncthreads();
    for (int b = t; b < NB; b += 256)
        histT[(size_t)b * C + c] = h[b];
}

// ---- generic 3-kernel exclusive scan (in-place safe), L <= 512*SCAN_CHUNK ----
__global__ void k_scan1(const int* __restrict__ in, int L,
                        int* __restrict__ part, int* __restrict__ blocksums) {
    __shared__ int lds[SCAN_CHUNK];
    __shared__ int tsum[256];
    int b = blockIdx.x, t = threadIdx.x;
    int base = b * SCAN_CHUNK;
    for (int i = t; i < SCAN_CHUNK; i += 256)
        lds[i] = (base + i < L) ? in[base + i] : 0;
    __syncthreads();
    int a0 = lds[t*4], a1 = lds[t*4+1], a2 = lds[t*4+2], a3 = lds[t*4+3];
    int ts = a0 + a1 + a2 + a3;
    tsum[t] = ts;
    __syncthreads();
    for (int off = 1; off < 256; off <<= 1) {
        int v = (t >= off) ? tsum[t - off] : 0;
        __syncthreads();
        tsum[t] += v;
        __syncthreads();
    }
    int excl = tsum[t] - ts;
    int i0 = base + t*4;
    if (i0     < L) part[i0]     = excl;
    if (i0 + 1 < L) part[i0 + 1] = excl + a0;
    if (i0 + 2 < L) part[i0 + 2] = excl + a0 + a1;
    if (i0 + 3 < L) part[i0 + 3] = excl + a0 + a1 + a2;
    if (t == 255) blocksums[b] = tsum[255];
}

__global__ void k_scan2(const int* __restrict__ blocksums, int nb, int* __restrict__ blockoff) {
    __shared__ int s[512];
    int t = threadIdx.x;    // 512 threads
    s[t] = (t < nb) ? blocksums[t] : 0;
    __syncthreads();
    int mine = s[t];
    for (int off = 1; off < 512; off <<= 1) {
        int v = (t >= off) ? s[t - off] : 0;
        __syncthreads();
        s[t] += v;
        __syncthreads();
    }
    blockoff[t] = s[t] - mine;   // exclusive
}

__global__ void k_scan3f(int* __restrict__ part, const int* __restrict__ blockoff, int L) {
    int i = blockIdx.x * blockDim.x + threadIdx.x;
    if (i < L) part[i] += blockoff[i / SCAN_CHUNK];
}

// ---- scatter edges into bin-grouped bucket; rank via LDS atomic, 8 chains ----
__global__ void k_scatterbin(const int* __restrict__ src, const int* __restrict__ dst,
                             int E, int C, int NB, const int* __restrict__ scanT,
                             int* __restrict__ bucket) {
    __shared__ int cur[MAXNB];
    int c = blockIdx.x, t = threadIdx.x;
    for (int b = t; b < NB; b += 256) cur[b] = scanT[(size_t)b * C + c];
    __syncthreads();
    int base = c * ECHUNK;
    int end = min(base + ECHUNK, E);
    int n4 = (end - base) >> 2;
    const int4* d4 = (const int4*)(dst + base);
    const int4* s4 = (const int4*)(src + base);
    for (int i = t; i < n4; i += 512) {
        int4 da = d4[i], sa = s4[i];
        bool hb = (i + 256) < n4;
        int4 db, sb;
        if (hb) { db = d4[i + 256]; sb = s4[i + 256]; }
        int r0 = atomicAdd(&cur[da.x >> BINSH], 1);
        int r1 = atomicAdd(&cur[da.y >> BINSH], 1);
        int r2 = atomicAdd(&cur[da.z >> BINSH], 1);
        int r3 = atomicAdd(&cur[da.w >> BINSH], 1);
        int r4 = 0, r5 = 0, r6 = 0, r7 = 0;
        if (hb) {
            r4 = atomicAdd(&cur[db.x >> BINSH], 1);
            r5 = atomicAdd(&cur[db.y >> BINSH], 1);
            r6 = atomicAdd(&cur[db.z >> BINSH], 1);
            r7 = atomicAdd(&cur[db.w >> BINSH], 1);
        }
        bucket[r0] = (sa.x << BINSH) | (da.x & (BINW - 1));
        bucket[r1] = (sa.y << BINSH) | (da.y & (BINW - 1));
        bucket[r2] = (sa.z << BINSH) | (da.z & (BINW - 1));
        bucket[r3] = (sa.w << BINSH) | (da.w & (BINW - 1));
        if (hb) {
            bucket[r4] = (sb.x << BINSH) | (db.x & (BINW - 1));
            bucket[r5] = (sb.y << BINSH) | (db.y & (BINW - 1));
            bucket[r6] = (sb.z << BINSH) | (db.z & (BINW - 1));
            bucket[r7] = (sb.w << BINSH) | (db.w & (BINW - 1));
        }
    }
}

// ---- per-bin CSR finalize: local degree count, scan, staged coalesced write ----
__global__ void k_csrbuild(const int* __restrict__ scanT, int C, int NB, int E,
                           const int* __restrict__ bucket, int* __restrict__ csr,
                           int* __restrict__ rowptr, float* __restrict__ dis, int N) {
    __shared__ int cnt[BINW];
    __shared__ int ex[BINW];
    __shared__ int cur[BINW];
    __shared__ int stage[STAGE_MAX];
    int b = blockIdx.x, t = threadIdx.x;
    int s = scanT[(size_t)b * C];
    int e = (b + 1 < NB) ? scanT[(size_t)(b + 1) * C] : E;
    int len = e - s;
    if (t < BINW) cnt[t] = 0;
    __syncthreads();
    for (int p = s + t; p < e; p += 256)
        atomicAdd(&cnt[bucket[p] & (BINW - 1)], 1);
    __syncthreads();
    if (t < BINW) ex[t] = cnt[t];
    __syncthreads();
    for (int off = 1; off < BINW; off <<= 1) {
        int v = (t < BINW && t >= off) ? ex[t - off] : 0;
        __syncthreads();
        if (t < BINW) ex[t] += v;
        __syncthreads();
    }
    if (t < BINW) {
        int excl = ex[t] - cnt[t];
        cur[t] = excl;
        int n = b * BINW + t;
        if (n <= N) rowptr[n] = s + excl;
        if (n < N)  dis[n] = rsqrtf((float)(cnt[t] + 1));
    }
    __syncthreads();
    if (len <= STAGE_MAX) {
        for (int p = s + t; p < e; p += 256) {
            int w = bucket[p];
            int r = atomicAdd(&cur[w & (BINW - 1)], 1);
            stage[r] = w >> BINSH;
        }
        __syncthreads();
        for (int i = t; i < len; i += 256) csr[s + i] = stage[i];
    } else {
        for (int p = s + t; p < e; p += 256) {
            int w = bucket[p];
            int r = atomicAdd(&cur[w & (BINW - 1)], 1);
            csr[s + r] = w >> BINSH;
        }
    }
}

// ---- xs[N][16] = dis[row] * x[row][0..10], padded with zeros ----
__global__ void k_xs(const float* __restrict__ x, const float* __restrict__ dis,
                     float* __restrict__ xs, int N) {
    int i = blockIdx.x * blockDim.x + threadIdx.x;
    if (i < N * XPAD) {
        int row = i >> 4, f = i & 15;
        xs[i] = (f < INC) ? dis[row] * x[row * INC + f] : 0.f;
    }
}

// ---- layer-1 x-space aggregation + W1 + relu + fused W2 -> g2 ----
// wave per row; lane = (edge-slot e=l>>4, feature f=l&15); 4 edges/load.
__global__ void k_agg1x(const int* __restrict__ rowptr, const int* __restrict__ csr,
                        const float* __restrict__ xs, const float* __restrict__ dis,
                        const float* __restrict__ W1, const float* __restrict__ b1,
                        const float* __restrict__ W2, float* __restrict__ g2, int N) {
    __shared__ float W1s[INC * HID];   // 2.75 KB
    __shared__ float W2s[HID * HID];   // 16 KB
    __shared__ float arow[4][HID];
    int t = threadIdx.x;
    for (int i = t; i < INC * HID; i += 256) W1s[i] = W1[i];
    for (int i = t; i < HID * HID; i += 256) W2s[i] = W2[i];
    __syncthreads();
    int lane = t & 63, wv = t >> 6;
    int row = (blockIdx.x * blockDim.x + t) >> 6;
    if (row >= N) return;
    int f = lane & 15, e = lane >> 4;
    int p0 = rowptr[row], p1 = rowptr[row + 1];
    float acc = 0.f;
    for (int p = p0; p < p1; p += 64) {
        int idx = (p + lane < p1) ? csr[p + lane] : 0;
        int ng = min(64, p1 - p);
        int j = 0;
        for (; j + 8 <= ng; j += 8) {          // 2 groups of 4 edges in flight
            int sa = __shfl(idx, j + e);
            int sb = __shfl(idx, j + 4 + e);
            float va = xs[(size_t)sa * XPAD + f];
            float vb = xs[(size_t)sb * XPAD + f];
            acc += va; acc += vb;
        }
        for (; j < ng; j += 4) {               // tail groups (partial)
            int q = j + e;
            int s_ = __shfl(idx, (q < ng) ? q : 0);
            float v = xs[(size_t)s_ * XPAD + f];
            acc += (q < ng) ? v : 0.f;
        }
    }
    // reduce the 4 edge-slot copies (same f stays together: xor 32, xor 16)
    acc += __shfl_xor(acc, 32);
    acc += __shfl_xor(acc, 16);
    acc += xs[(size_t)row * XPAD + f];         // self-loop term (xs_i)
    float d = dis[row];
    // pre1[lane] = (xagg @ W1)[lane]
    float pre = 0.f;
    #pragma unroll
    for (int k = 0; k < INC; ++k)
        pre += __shfl(acc, k) * W1s[k * HID + lane];
    float a = d * pre + b1[lane];
    a = a > 0.f ? a : 0.f;
    arow[wv][lane] = a;                        // wave-internal exchange
    float acc2 = 0.f;
    #pragma unroll
    for (int k = 0; k < HID; k += 4) {
        float a0 = arow[wv][k], a1 = arow[wv][k+1], a2 = arow[wv][k+2], a3 = arow[wv][k+3];
        acc2 += a0 * W2s[(k    ) * HID + lane];
        acc2 += a1 * W2s[(k + 1) * HID + lane];
        acc2 += a2 * W2s[(k + 2) * HID + lane];
        acc2 += a3 * W2s[(k + 3) * HID + lane];
    }
    g2[(size_t)row * HID + lane] = d * acc2;
}

// ---- layer-2 aggregation (h-space) fused with head ----
__device__ __forceinline__ float agg_row(const int* __restrict__ rowptr,
                                         const int* __restrict__ csr,
                                         const float* __restrict__ g,
                                         int row, int lane) {
    int s = rowptr[row], e = rowptr[row + 1];
    float acc = g[(size_t)row * HID + lane];   // self-loop (dis folded in g)
    for (int p = s; p < e; p += 64) {
        int idx = (p + lane < e) ? csr[p + lane] : 0;
        int cnt = min(64, e - p);
        int j = 0;
        for (; j + 7 < cnt; j += 8) {
            int s0 = __shfl(idx, j);
            int s1 = __shfl(idx, j + 1);
            int s2 = __shfl(idx, j + 2);
            int s3 = __shfl(idx, j + 3);
            int s4 = __shfl(idx, j + 4);
            int s5 = __shfl(idx, j + 5);
            int s6 = __shfl(idx, j + 6);
            int s7 = __shfl(idx, j + 7);
            float v0 = g[(size_t)s0 * HID + lane];
            float v1 = g[(size_t)s1 * HID + lane];
            float v2 = g[(size_t)s2 * HID + lane];
            float v3 = g[(size_t)s3 * HID + lane];
            float v4 = g[(size_t)s4 * HID + lane];
            float v5 = g[(size_t)s5 * HID + lane];
            float v6 = g[(size_t)s6 * HID + lane];
            float v7 = g[(size_t)s7 * HID + lane];
            acc += v0; acc += v1; acc += v2; acc += v3;
            acc += v4; acc += v5; acc += v6; acc += v7;
        }
        for (; j < cnt; ++j)
            acc += g[(size_t)__shfl(idx, j) * HID + lane];
    }
    return acc;
}

__global__ void k_agg2_head(const int* __restrict__ rowptr, const int* __restrict__ csr,
                            const float* __restrict__ g, const float* __restrict__ dis,
                            const float* __restrict__ b, const float* __restrict__ Wl,
                            const float* __restrict__ bl, float* __restrict__ out, int N) {
    int lane = threadIdx.x & 63;
    int row = (blockIdx.x * blockDim.x + threadIdx.x) >> 6;
    if (row >= N) return;
    float acc = agg_row(rowptr, csr, g, row, lane);
    float v = dis[row] * acc + b[lane];
    v = v > 0.f ? v : 0.f;
    v *= Wl[lane];
    #pragma unroll
    for (int off = 32; off > 0; off >>= 1) v += __shfl_down(v, off);
    if (lane == 0) out[row] = v + bl[0];
}

extern "C" void kernel_launch(void* const* d_in, const int* in_sizes, int n_in,
                              void* d_out, int out_size, void* d_ws, size_t ws_size,
                              hipStream_t stream) {
    const float* x  = (const float*)d_in[0];
    const int*   ei = (const int*)d_in[1];
    const float* W1 = (const float*)d_in[2];
    const float* b1 = (const float*)d_in[3];
    const float* W2 = (const float*)d_in[4];
    const float* b2 = (const float*)d_in[5];
    const float* Wl = (const float*)d_in[6];
    const float* bl = (const float*)d_in[7];
    float* out = (float*)d_out;

    const int N = in_sizes[0] / INC;    // 100000
    const int E = in_sizes[1] / 2;      // 3200000
    const int NB = (N + BINW - 1) / BINW;        // 782
    const int C  = (E + ECHUNK - 1) / ECHUNK;    // 391
    const int L  = NB * C;                        // 305762
    const int nScan = (L + SCAN_CHUNK - 1) / SCAN_CHUNK;  // 299 (<=512)

    char* ws = (char*)d_ws;
    size_t off = 0;
    auto alloc = [&](size_t bytes) { void* p = ws + off; off += (bytes + 255) / 256 * 256; return p; };
    int*   histT    = (int*)alloc((size_t)L * 4);     // scanned in place
    int*   blocksums= (int*)alloc(512 * 4);
    int*   blockoff = (int*)alloc(512 * 4);
    int*   rowptr   = (int*)alloc((size_t)(N + 1) * 4);
    float* dis      = (float*)alloc((size_t)N * 4);
    int*   csr      = (int*)alloc((size_t)E * 4);
    int*   bucket   = (int*)alloc((size_t)E * 4);
    float* xs       = (float*)alloc((size_t)N * XPAD * 4);   // 6.4 MB
    float* bufG2    = (float*)alloc((size_t)N * HID * 4);    // 25.6 MB

    const int TPB = 256;
    const int* esrc = ei;
    const int* edst = ei + E;
    const int waveBlocks = ((size_t)N * 64 + TPB - 1) / TPB;

    // CSR build — zero global atomics
    k_hist<<<C, TPB, 0, stream>>>(edst, E, C, NB, histT);
    k_scan1<<<nScan, TPB, 0, stream>>>(histT, L, histT, blocksums);
    k_scan2<<<1, 512, 0, stream>>>(blocksums, nScan, blockoff);
    k_scan3f<<<(L + TPB - 1) / TPB, TPB, 0, stream>>>(histT, blockoff, L);
    k_scatterbin<<<C, TPB, 0, stream>>>(esrc, edst, E, C, NB, histT, bucket);
    k_csrbuild<<<NB, TPB, 0, stream>>>(histT, C, NB, E, bucket, csr, rowptr, dis, N);

    // xs table (needs dis)
    k_xs<<<((N * XPAD) + TPB - 1) / TPB, TPB, 0, stream>>>(x, dis, xs, N);

    // layer 1: x-space aggregation + W1 + relu + fused W2 -> g2
    k_agg1x<<<waveBlocks, TPB, 0, stream>>>(rowptr, csr, xs, dis, W1, b1, W2, bufG2, N);

    // layer 2: h-space aggregation + head
    k_agg2_head<<<waveBlocks, TPB, 0, stream>>>(rowptr, csr, bufG2, dis, b2, Wl, bl, out, N);
}

// Round 12
// 229.337 us; speedup vs baseline: 18.6694x; 1.1881x over previous
//
#include <hip/hip_runtime.h>

// GCN 2-layer + head.
// R12: R11 + bf16 gather tables. xs (layer-1 x-space table) = N x 16 bf16
//      = 3.2 MB (fully L2-resident per XCD); g2 (layer-2 h-space table) =
//      N x 64 bf16 = 12.8 MB (halves agg2's fill traffic, which R11 showed
//      is the binding constraint at ~3.7 TB/s). All accumulation stays f32;
//      bf16 conversion is round-to-nearest-even.
// bucket word = (src<<7) | (dst&127), src < 2^17 fits 24 bits.

#define HID 64
#define INC 11
#define XPAD 16
#define BINSH 7
#define BINW 128
#define MAXNB 800      // >= ceil(100000/128)=782
#define ECHUNK 8192
#define SCAN_CHUNK 1024
#define STAGE_MAX 6144

typedef unsigned short bf16t;

__device__ __forceinline__ float b2f(bf16t u) {
    union { float f; unsigned int i; } v;
    v.i = ((unsigned int)u) << 16;
    return v.f;
}
__device__ __forceinline__ bf16t f2b(float f) {
    union { float ff; unsigned int i; } v;
    v.ff = f;
    unsigned int r = v.i + 0x7FFF + ((v.i >> 16) & 1);   // RNE
    return (bf16t)(r >> 16);
}

// ---- per-chunk histogram of dst bins, stored transposed histT[b*C+c] ----
__global__ void k_hist(const int* __restrict__ dst, int E, int C, int NB,
                       int* __restrict__ histT) {
    __shared__ int h[MAXNB];
    int c = blockIdx.x, t = threadIdx.x;
    for (int i = t; i < NB; i += 256) h[i] = 0;
    __syncthreads();
    int base = c * ECHUNK;
    int end = min(base + ECHUNK, E);
    int n4 = (end - base) >> 2;
    const int4* d4 = (const int4*)(dst + base);
    for (int i = t; i < n4; i += 256) {
        int4 d = d4[i];
        atomicAdd(&h[d.x >> BINSH], 1);
        atomicAdd(&h[d.y >> BINSH], 1);
        atomicAdd(&h[d.z >> BINSH], 1);
        atomicAdd(&h[d.w >> BINSH], 1);
    }
    __syncthreads();
    for (int b = t; b < NB; b += 256)
        histT[(size_t)b * C + c] = h[b];
}

// ---- generic 3-kernel exclusive scan (in-place safe), L <= 512*SCAN_CHUNK ----
__global__ void k_scan1(const int* __restrict__ in, int L,
                        int* __restrict__ part, int* __restrict__ blocksums) {
    __shared__ int lds[SCAN_CHUNK];
    __shared__ int tsum[256];
    int b = blockIdx.x, t = threadIdx.x;
    int base = b * SCAN_CHUNK;
    for (int i = t; i < SCAN_CHUNK; i += 256)
        lds[i] = (base + i < L) ? in[base + i] : 0;
    __syncthreads();
    int a0 = lds[t*4], a1 = lds[t*4+1], a2 = lds[t*4+2], a3 = lds[t*4+3];
    int ts = a0 + a1 + a2 + a3;
    tsum[t] = ts;
    __syncthreads();
    for (int off = 1; off < 256; off <<= 1) {
        int v = (t >= off) ? tsum[t - off] : 0;
        __syncthreads();
        tsum[t] += v;
        __syncthreads();
    }
    int excl = tsum[t] - ts;
    int i0 = base + t*4;
    if (i0     < L) part[i0]     = excl;
    if (i0 + 1 < L) part[i0 + 1] = excl + a0;
    if (i0 + 2 < L) part[i0 + 2] = excl + a0 + a1;
    if (i0 + 3 < L) part[i0 + 3] = excl + a0 + a1 + a2;
    if (t == 255) blocksums[b] = tsum[255];
}

__global__ void k_scan2(const int* __restrict__ blocksums, int nb, int* __restrict__ blockoff) {
    __shared__ int s[512];
    int t = threadIdx.x;    // 512 threads
    s[t] = (t < nb) ? blocksums[t] : 0;
    __syncthreads();
    int mine = s[t];
    for (int off = 1; off < 512; off <<= 1) {
        int v = (t >= off) ? s[t - off] : 0;
        __syncthreads();
        s[t] += v;
        __syncthreads();
    }
    blockoff[t] = s[t] - mine;   // exclusive
}

__global__ void k_scan3f(int* __restrict__ part, const int* __restrict__ blockoff, int L) {
    int i = blockIdx.x * blockDim.x + threadIdx.x;
    if (i < L) part[i] += blockoff[i / SCAN_CHUNK];
}

// ---- scatter edges into bin-grouped bucket; rank via LDS atomic, 8 chains ----
__global__ void k_scatterbin(const int* __restrict__ src, const int* __restrict__ dst,
                             int E, int C, int NB, const int* __restrict__ scanT,
                             int* __restrict__ bucket) {
    __shared__ int cur[MAXNB];
    int c = blockIdx.x, t = threadIdx.x;
    for (int b = t; b < NB; b += 256) cur[b] = scanT[(size_t)b * C + c];
    __syncthreads();
    int base = c * ECHUNK;
    int end = min(base + ECHUNK, E);
    int n4 = (end - base) >> 2;
    const int4* d4 = (const int4*)(dst + base);
    const int4* s4 = (const int4*)(src + base);
    for (int i = t; i < n4; i += 512) {
        int4 da = d4[i], sa = s4[i];
        bool hb = (i + 256) < n4;
        int4 db, sb;
        if (hb) { db = d4[i + 256]; sb = s4[i + 256]; }
        int r0 = atomicAdd(&cur[da.x >> BINSH], 1);
        int r1 = atomicAdd(&cur[da.y >> BINSH], 1);
        int r2 = atomicAdd(&cur[da.z >> BINSH], 1);
        int r3 = atomicAdd(&cur[da.w >> BINSH], 1);
        int r4 = 0, r5 = 0, r6 = 0, r7 = 0;
        if (hb) {
            r4 = atomicAdd(&cur[db.x >> BINSH], 1);
            r5 = atomicAdd(&cur[db.y >> BINSH], 1);
            r6 = atomicAdd(&cur[db.z >> BINSH], 1);
            r7 = atomicAdd(&cur[db.w >> BINSH], 1);
        }
        bucket[r0] = (sa.x << BINSH) | (da.x & (BINW - 1));
        bucket[r1] = (sa.y << BINSH) | (da.y & (BINW - 1));
        bucket[r2] = (sa.z << BINSH) | (da.z & (BINW - 1));
        bucket[r3] = (sa.w << BINSH) | (da.w & (BINW - 1));
        if (hb) {
            bucket[r4] = (sb.x << BINSH) | (db.x & (BINW - 1));
            bucket[r5] = (sb.y << BINSH) | (db.y & (BINW - 1));
            bucket[r6] = (sb.z << BINSH) | (db.z & (BINW - 1));
            bucket[r7] = (sb.w << BINSH) | (db.w & (BINW - 1));
        }
    }
}

// ---- per-bin CSR finalize: local degree count, scan, staged coalesced write ----
__global__ void k_csrbuild(const int* __restrict__ scanT, int C, int NB, int E,
                           const int* __restrict__ bucket, int* __restrict__ csr,
                           int* __restrict__ rowptr, float* __restrict__ dis, int N) {
    __shared__ int cnt[BINW];
    __shared__ int ex[BINW];
    __shared__ int cur[BINW];
    __shared__ int stage[STAGE_MAX];
    int b = blockIdx.x, t = threadIdx.x;
    int s = scanT[(size_t)b * C];
    int e = (b + 1 < NB) ? scanT[(size_t)(b + 1) * C] : E;
    int len = e - s;
    if (t < BINW) cnt[t] = 0;
    __syncthreads();
    for (int p = s + t; p < e; p += 256)
        atomicAdd(&cnt[bucket[p] & (BINW - 1)], 1);
    __syncthreads();
    if (t < BINW) ex[t] = cnt[t];
    __syncthreads();
    for (int off = 1; off < BINW; off <<= 1) {
        int v = (t < BINW && t >= off) ? ex[t - off] : 0;
        __syncthreads();
        if (t < BINW) ex[t] += v;
        __syncthreads();
    }
    if (t < BINW) {
        int excl = ex[t] - cnt[t];
        cur[t] = excl;
        int n = b * BINW + t;
        if (n <= N) rowptr[n] = s + excl;
        if (n < N)  dis[n] = rsqrtf((float)(cnt[t] + 1));
    }
    __syncthreads();
    if (len <= STAGE_MAX) {
        for (int p = s + t; p < e; p += 256) {
            int w = bucket[p];
            int r = atomicAdd(&cur[w & (BINW - 1)], 1);
            stage[r] = w >> BINSH;
        }
        __syncthreads();
        for (int i = t; i < len; i += 256) csr[s + i] = stage[i];
    } else {
        for (int p = s + t; p < e; p += 256) {
            int w = bucket[p];
            int r = atomicAdd(&cur[w & (BINW - 1)], 1);
            csr[s + r] = w >> BINSH;
        }
    }
}

// ---- xs[N][16] = bf16(dis[row] * x[row][0..10]), padded with zeros ----
__global__ void k_xs(const float* __restrict__ x, const float* __restrict__ dis,
                     bf16t* __restrict__ xs, int N) {
    int i = blockIdx.x * blockDim.x + threadIdx.x;
    if (i < N * XPAD) {
        int row = i >> 4, f = i & 15;
        float v = (f < INC) ? dis[row] * x[row * INC + f] : 0.f;
        xs[i] = f2b(v);
    }
}

// ---- layer-1 x-space aggregation + W1 + relu + fused W2 -> g2 (bf16) ----
// wave per row; lane = (edge-slot e=l>>4, feature f=l&15); 4 edges/load.
__global__ void k_agg1x(const int* __restrict__ rowptr, const int* __restrict__ csr,
                        const bf16t* __restrict__ xs, const float* __restrict__ dis,
                        const float* __restrict__ W1, const float* __restrict__ b1,
                        const float* __restrict__ W2, bf16t* __restrict__ g2, int N) {
    __shared__ float W1s[INC * HID];   // 2.75 KB
    __shared__ float W2s[HID * HID];   // 16 KB
    __shared__ float arow[4][HID];
    int t = threadIdx.x;
    for (int i = t; i < INC * HID; i += 256) W1s[i] = W1[i];
    for (int i = t; i < HID * HID; i += 256) W2s[i] = W2[i];
    __syncthreads();
    int lane = t & 63, wv = t >> 6;
    int row = (blockIdx.x * blockDim.x + t) >> 6;
    if (row >= N) return;
    int f = lane & 15, e = lane >> 4;
    int p0 = rowptr[row], p1 = rowptr[row + 1];
    float acc = 0.f;
    for (int p = p0; p < p1; p += 64) {
        int idx = (p + lane < p1) ? csr[p + lane] : 0;
        int ng = min(64, p1 - p);
        int j = 0;
        for (; j + 8 <= ng; j += 8) {          // 2 groups of 4 edges in flight
            int sa = __shfl(idx, j + e);
            int sb = __shfl(idx, j + 4 + e);
            bf16t ua = xs[(size_t)sa * XPAD + f];
            bf16t ub = xs[(size_t)sb * XPAD + f];
            acc += b2f(ua); acc += b2f(ub);
        }
        for (; j < ng; j += 4) {               // tail groups (partial)
            int q = j + e;
            int s_ = __shfl(idx, (q < ng) ? q : 0);
            bf16t u = xs[(size_t)s_ * XPAD + f];
            acc += (q < ng) ? b2f(u) : 0.f;
        }
    }
    // reduce the 4 edge-slot copies (same f stays together: xor 32, xor 16)
    acc += __shfl_xor(acc, 32);
    acc += __shfl_xor(acc, 16);
    acc += b2f(xs[(size_t)row * XPAD + f]);    // self-loop term (xs_i)
    float d = dis[row];
    // pre1[lane] = (xagg @ W1)[lane]
    float pre = 0.f;
    #pragma unroll
    for (int k = 0; k < INC; ++k)
        pre += __shfl(acc, k) * W1s[k * HID + lane];
    float a = d * pre + b1[lane];
    a = a > 0.f ? a : 0.f;
    arow[wv][lane] = a;                        // wave-internal exchange
    float acc2 = 0.f;
    #pragma unroll
    for (int k = 0; k < HID; k += 4) {
        float a0 = arow[wv][k], a1 = arow[wv][k+1], a2 = arow[wv][k+2], a3 = arow[wv][k+3];
        acc2 += a0 * W2s[(k    ) * HID + lane];
        acc2 += a1 * W2s[(k + 1) * HID + lane];
        acc2 += a2 * W2s[(k + 2) * HID + lane];
        acc2 += a3 * W2s[(k + 3) * HID + lane];
    }
    g2[(size_t)row * HID + lane] = f2b(d * acc2);
}

// ---- layer-2 aggregation (bf16 table) fused with head ----
__device__ __forceinline__ float agg_row_b(const int* __restrict__ rowptr,
                                           const int* __restrict__ csr,
                                           const bf16t* __restrict__ g,
                                           int row, int lane) {
    int s = rowptr[row], e = rowptr[row + 1];
    float acc = b2f(g[(size_t)row * HID + lane]);   // self-loop
    for (int p = s; p < e; p += 64) {
        int idx = (p + lane < e) ? csr[p + lane] : 0;
        int cnt = min(64, e - p);
        int j = 0;
        for (; j + 7 < cnt; j += 8) {
            int s0 = __shfl(idx, j);
            int s1 = __shfl(idx, j + 1);
            int s2 = __shfl(idx, j + 2);
            int s3 = __shfl(idx, j + 3);
            int s4 = __shfl(idx, j + 4);
            int s5 = __shfl(idx, j + 5);
            int s6 = __shfl(idx, j + 6);
            int s7 = __shfl(idx, j + 7);
            bf16t v0 = g[(size_t)s0 * HID + lane];
            bf16t v1 = g[(size_t)s1 * HID + lane];
            bf16t v2 = g[(size_t)s2 * HID + lane];
            bf16t v3 = g[(size_t)s3 * HID + lane];
            bf16t v4 = g[(size_t)s4 * HID + lane];
            bf16t v5 = g[(size_t)s5 * HID + lane];
            bf16t v6 = g[(size_t)s6 * HID + lane];
            bf16t v7 = g[(size_t)s7 * HID + lane];
            acc += b2f(v0); acc += b2f(v1); acc += b2f(v2); acc += b2f(v3);
            acc += b2f(v4); acc += b2f(v5); acc += b2f(v6); acc += b2f(v7);
        }
        for (; j < cnt; ++j)
            acc += b2f(g[(size_t)__shfl(idx, j) * HID + lane]);
    }
    return acc;
}

__global__ void k_agg2_head(const int* __restrict__ rowptr, const int* __restrict__ csr,
                            const bf16t* __restrict__ g, const float* __restrict__ dis,
                            const float* __restrict__ b, const float* __restrict__ Wl,
                            const float* __restrict__ bl, float* __restrict__ out, int N) {
    int lane = threadIdx.x & 63;
    int row = (blockIdx.x * blockDim.x + threadIdx.x) >> 6;
    if (row >= N) return;
    float acc = agg_row_b(rowptr, csr, g, row, lane);
    float v = dis[row] * acc + b[lane];
    v = v > 0.f ? v : 0.f;
    v *= Wl[lane];
    #pragma unroll
    for (int off = 32; off > 0; off >>= 1) v += __shfl_down(v, off);
    if (lane == 0) out[row] = v + bl[0];
}

extern "C" void kernel_launch(void* const* d_in, const int* in_sizes, int n_in,
                              void* d_out, int out_size, void* d_ws, size_t ws_size,
                              hipStream_t stream) {
    const float* x  = (const float*)d_in[0];
    const int*   ei = (const int*)d_in[1];
    const float* W1 = (const float*)d_in[2];
    const float* b1 = (const float*)d_in[3];
    const float* W2 = (const float*)d_in[4];
    const float* b2 = (const float*)d_in[5];
    const float* Wl = (const float*)d_in[6];
    const float* bl = (const float*)d_in[7];
    float* out = (float*)d_out;

    const int N = in_sizes[0] / INC;    // 100000
    const int E = in_sizes[1] / 2;      // 3200000
    const int NB = (N + BINW - 1) / BINW;        // 782
    const int C  = (E + ECHUNK - 1) / ECHUNK;    // 391
    const int L  = NB * C;                        // 305762
    const int nScan = (L + SCAN_CHUNK - 1) / SCAN_CHUNK;  // 299 (<=512)

    char* ws = (char*)d_ws;
    size_t off = 0;
    auto alloc = [&](size_t bytes) { void* p = ws + off; off += (bytes + 255) / 256 * 256; return p; };
    int*   histT    = (int*)alloc((size_t)L * 4);     // scanned in place
    int*   blocksums= (int*)alloc(512 * 4);
    int*   blockoff = (int*)alloc(512 * 4);
    int*   rowptr   = (int*)alloc((size_t)(N + 1) * 4);
    float* dis      = (float*)alloc((size_t)N * 4);
    int*   csr      = (int*)alloc((size_t)E * 4);
    int*   bucket   = (int*)alloc((size_t)E * 4);
    bf16t* xs       = (bf16t*)alloc((size_t)N * XPAD * 2);   // 3.2 MB
    bf16t* g2       = (bf16t*)alloc((size_t)N * HID * 2);    // 12.8 MB

    const int TPB = 256;
    const int* esrc = ei;
    const int* edst = ei + E;
    const int waveBlocks = ((size_t)N * 64 + TPB - 1) / TPB;

    // CSR build — zero global atomics
    k_hist<<<C, TPB, 0, stream>>>(edst, E, C, NB, histT);
    k_scan1<<<nScan, TPB, 0, stream>>>(histT, L, histT, blocksums);
    k_scan2<<<1, 512, 0, stream>>>(blocksums, nScan, blockoff);
    k_scan3f<<<(L + TPB - 1) / TPB, TPB, 0, stream>>>(histT, blockoff, L);
    k_scatterbin<<<C, TPB, 0, stream>>>(esrc, edst, E, C, NB, histT, bucket);
    k_csrbuild<<<NB, TPB, 0, stream>>>(histT, C, NB, E, bucket, csr, rowptr, dis, N);

    // xs table (needs dis)
    k_xs<<<((N * XPAD) + TPB - 1) / TPB, TPB, 0, stream>>>(x, dis, xs, N);

    // layer 1: x-space aggregation + W1 + relu + fused W2 -> g2 (bf16)
    k_agg1x<<<waveBlocks, TPB, 0, stream>>>(rowptr, csr, xs, dis, W1, b1, W2, g2, N);

    // layer 2: h-space aggregation + head
    k_agg2_head<<<waveBlocks, TPB, 0, stream>>>(rowptr, csr, g2, dis, b2, Wl, bl, out, N);
}

// Round 15
// 216.428 us; speedup vs baseline: 19.7829x; 1.0596x over previous
//
#include <hip/hip_runtime.h>

// GCN 2-layer + head.
// R15: R14 with the agg2_head bug fixed — self-loop octet must be added
//      AFTER the 8-slot shfl_xor reduction (R13/R14 added it before, so it
//      was counted 8x -> absmax 0.138 in both, bit-identical => shared bug).
//      (a) agg1x: packed pair gather (8 lanes/edge), f32 accum, W1 + relu +
//          float4-vectorized W2T matvec epilogue (exact f32);
//      (b) agg2: packed uint4 gather (8 bf16/lane, 8 lanes/edge), f32 accum,
//          fused head.
// bucket word = (src<<7) | (dst&127), src < 2^17 fits 24 bits.

#define HID 64
#define INC 11
#define XPAD 16
#define BINSH 7
#define BINW 128
#define MAXNB 800      // >= ceil(100000/128)=782
#define ECHUNK 8192
#define SCAN_CHUNK 1024
#define STAGE_MAX 6144

typedef unsigned short bf16t;

__device__ __forceinline__ float b2f(bf16t u) {
    union { float f; unsigned int i; } v;
    v.i = ((unsigned int)u) << 16;
    return v.f;
}
__device__ __forceinline__ bf16t f2b(float f) {
    union { float ff; unsigned int i; } v;
    v.ff = f;
    unsigned int r = v.i + 0x7FFF + ((v.i >> 16) & 1);   // RNE
    return (bf16t)(r >> 16);
}
__device__ __forceinline__ float blo(unsigned int u) {
    union { float f; unsigned int i; } v; v.i = u << 16; return v.f;
}
__device__ __forceinline__ float bhi(unsigned int u) {
    union { float f; unsigned int i; } v; v.i = u & 0xFFFF0000u; return v.f;
}

// ---- per-chunk histogram of dst bins, stored transposed histT[b*C+c] ----
__global__ void k_hist(const int* __restrict__ dst, int E, int C, int NB,
                       int* __restrict__ histT) {
    __shared__ int h[MAXNB];
    int c = blockIdx.x, t = threadIdx.x;
    for (int i = t; i < NB; i += 256) h[i] = 0;
    __syncthreads();
    int base = c * ECHUNK;
    int end = min(base + ECHUNK, E);
    int n4 = (end - base) >> 2;
    const int4* d4 = (const int4*)(dst + base);
    for (int i = t; i < n4; i += 256) {
        int4 d = d4[i];
        atomicAdd(&h[d.x >> BINSH], 1);
        atomicAdd(&h[d.y >> BINSH], 1);
        atomicAdd(&h[d.z >> BINSH], 1);
        atomicAdd(&h[d.w >> BINSH], 1);
    }
    __syncthreads();
    for (int b = t; b < NB; b += 256)
        histT[(size_t)b * C + c] = h[b];
}

// ---- generic 3-kernel exclusive scan (in-place safe), L <= 512*SCAN_CHUNK ----
__global__ void k_scan1(const int* __restrict__ in, int L,
                        int* __restrict__ part, int* __restrict__ blocksums) {
    __shared__ int lds[SCAN_CHUNK];
    __shared__ int tsum[256];
    int b = blockIdx.x, t = threadIdx.x;
    int base = b * SCAN_CHUNK;
    for (int i = t; i < SCAN_CHUNK; i += 256)
        lds[i] = (base + i < L) ? in[base + i] : 0;
    __syncthreads();
    int a0 = lds[t*4], a1 = lds[t*4+1], a2 = lds[t*4+2], a3 = lds[t*4+3];
    int ts = a0 + a1 + a2 + a3;
    tsum[t] = ts;
    __syncthreads();
    for (int off = 1; off < 256; off <<= 1) {
        int v = (t >= off) ? tsum[t - off] : 0;
        __syncthreads();
        tsum[t] += v;
        __syncthreads();
    }
    int excl = tsum[t] - ts;
    int i0 = base + t*4;
    if (i0     < L) part[i0]     = excl;
    if (i0 + 1 < L) part[i0 + 1] = excl + a0;
    if (i0 + 2 < L) part[i0 + 2] = excl + a0 + a1;
    if (i0 + 3 < L) part[i0 + 3] = excl + a0 + a1 + a2;
    if (t == 255) blocksums[b] = tsum[255];
}

__global__ void k_scan2(const int* __restrict__ blocksums, int nb, int* __restrict__ blockoff) {
    __shared__ int s[512];
    int t = threadIdx.x;    // 512 threads
    s[t] = (t < nb) ? blocksums[t] : 0;
    __syncthreads();
    int mine = s[t];
    for (int off = 1; off < 512; off <<= 1) {
        int v = (t >= off) ? s[t - off] : 0;
        __syncthreads();
        s[t] += v;
        __syncthreads();
    }
    blockoff[t] = s[t] - mine;   // exclusive
}

__global__ void k_scan3f(int* __restrict__ part, const int* __restrict__ blockoff, int L) {
    int i = blockIdx.x * blockDim.x + threadIdx.x;
    if (i < L) part[i] += blockoff[i / SCAN_CHUNK];
}

// ---- scatter edges into bin-grouped bucket; rank via LDS atomic, 8 chains ----
__global__ void k_scatterbin(const int* __restrict__ src, const int* __restrict__ dst,
                             int E, int C, int NB, const int* __restrict__ scanT,
                             int* __restrict__ bucket) {
    __shared__ int cur[MAXNB];
    int c = blockIdx.x, t = threadIdx.x;
    for (int b = t; b < NB; b += 256) cur[b] = scanT[(size_t)b * C + c];
    __syncthreads();
    int base = c * ECHUNK;
    int end = min(base + ECHUNK, E);
    int n4 = (end - base) >> 2;
    const int4* d4 = (const int4*)(dst + base);
    const int4* s4 = (const int4*)(src + base);
    for (int i = t; i < n4; i += 512) {
        int4 da = d4[i], sa = s4[i];
        bool hb = (i + 256) < n4;
        int4 db, sb;
        if (hb) { db = d4[i + 256]; sb = s4[i + 256]; }
        int r0 = atomicAdd(&cur[da.x >> BINSH], 1);
        int r1 = atomicAdd(&cur[da.y >> BINSH], 1);
        int r2 = atomicAdd(&cur[da.z >> BINSH], 1);
        int r3 = atomicAdd(&cur[da.w >> BINSH], 1);
        int r4 = 0, r5 = 0, r6 = 0, r7 = 0;
        if (hb) {
            r4 = atomicAdd(&cur[db.x >> BINSH], 1);
            r5 = atomicAdd(&cur[db.y >> BINSH], 1);
            r6 = atomicAdd(&cur[db.z >> BINSH], 1);
            r7 = atomicAdd(&cur[db.w >> BINSH], 1);
        }
        bucket[r0] = (sa.x << BINSH) | (da.x & (BINW - 1));
        bucket[r1] = (sa.y << BINSH) | (da.y & (BINW - 1));
        bucket[r2] = (sa.z << BINSH) | (da.z & (BINW - 1));
        bucket[r3] = (sa.w << BINSH) | (da.w & (BINW - 1));
        if (hb) {
            bucket[r4] = (sb.x << BINSH) | (db.x & (BINW - 1));
            bucket[r5] = (sb.y << BINSH) | (db.y & (BINW - 1));
            bucket[r6] = (sb.z << BINSH) | (db.z & (BINW - 1));
            bucket[r7] = (sb.w << BINSH) | (db.w & (BINW - 1));
        }
    }
}

// ---- per-bin CSR finalize: local degree count, scan, staged coalesced write ----
__global__ void k_csrbuild(const int* __restrict__ scanT, int C, int NB, int E,
                           const int* __restrict__ bucket, int* __restrict__ csr,
                           int* __restrict__ rowptr, float* __restrict__ dis, int N) {
    __shared__ int cnt[BINW];
    __shared__ int ex[BINW];
    __shared__ int cur[BINW];
    __shared__ int stage[STAGE_MAX];
    int b = blockIdx.x, t = threadIdx.x;
    int s = scanT[(size_t)b * C];
    int e = (b + 1 < NB) ? scanT[(size_t)(b + 1) * C] : E;
    int len = e - s;
    if (t < BINW) cnt[t] = 0;
    __syncthreads();
    for (int p = s + t; p < e; p += 256)
        atomicAdd(&cnt[bucket[p] & (BINW - 1)], 1);
    __syncthreads();
    if (t < BINW) ex[t] = cnt[t];
    __syncthreads();
    for (int off = 1; off < BINW; off <<= 1) {
        int v = (t < BINW && t >= off) ? ex[t - off] : 0;
        __syncthreads();
        if (t < BINW) ex[t] += v;
        __syncthreads();
    }
    if (t < BINW) {
        int excl = ex[t] - cnt[t];
        cur[t] = excl;
        int n = b * BINW + t;
        if (n <= N) rowptr[n] = s + excl;
        if (n < N)  dis[n] = rsqrtf((float)(cnt[t] + 1));
    }
    __syncthreads();
    if (len <= STAGE_MAX) {
        for (int p = s + t; p < e; p += 256) {
            int w = bucket[p];
            int r = atomicAdd(&cur[w & (BINW - 1)], 1);
            stage[r] = w >> BINSH;
        }
        __syncthreads();
        for (int i = t; i < len; i += 256) csr[s + i] = stage[i];
    } else {
        for (int p = s + t; p < e; p += 256) {
            int w = bucket[p];
            int r = atomicAdd(&cur[w & (BINW - 1)], 1);
            csr[s + r] = w >> BINSH;
        }
    }
}

// ---- xs[N][16] = bf16(dis[row] * x[row][0..10]), padded with zeros ----
__global__ void k_xs(const float* __restrict__ x, const float* __restrict__ dis,
                     bf16t* __restrict__ xs, int N) {
    int i = blockIdx.x * blockDim.x + threadIdx.x;
    if (i < N * XPAD) {
        int row = i >> 4, f = i & 15;
        float v = (f < INC) ? dis[row] * x[row * INC + f] : 0.f;
        xs[i] = f2b(v);
    }
}

// ---- layer-1: packed x-space gather + W1 + relu + vectorized W2 matvec ----
// gather: lane = (slot = l>>3 of 8 edges, pair = l&7 -> features 2p, 2p+1).
__global__ void k_agg1x(const int* __restrict__ rowptr, const int* __restrict__ csr,
                        const bf16t* __restrict__ xs, const float* __restrict__ dis,
                        const float* __restrict__ W1, const float* __restrict__ b1,
                        const float* __restrict__ W2, bf16t* __restrict__ g2, int N) {
    __shared__ float W1s[INC * HID];                     // 2.75 KB
    __shared__ __align__(16) float W2Ts[HID][HID + 4];   // 17 KB, W2Ts[n][k]
    __shared__ __align__(16) float arow[4][HID];
    int t = threadIdx.x;
    for (int i = t; i < INC * HID; i += 256) W1s[i] = W1[i];
    for (int i = t; i < HID * HID; i += 256) W2Ts[i & 63][i >> 6] = W2[i];
    __syncthreads();
    int lane = t & 63, wv = t >> 6;
    int row = (blockIdx.x * blockDim.x + t) >> 6;
    if (row >= N) return;
    int pr = lane & 7;       // feature pair: features 2*pr, 2*pr+1
    int slot = lane >> 3;    // 8 edge slots
    int p0 = rowptr[row], p1 = rowptr[row + 1];
    float a0 = 0.f, a1 = 0.f;
    for (int p = p0; p < p1; p += 64) {
        int idx = (p + lane < p1) ? csr[p + lane] : 0;
        int cnt = min(64, p1 - p);
        for (int j = 0; j * 8 < cnt; ++j) {
            int q = j * 8 + slot;
            int srcn = __shfl(idx, q);       // idx beyond cnt is 0 (safe addr)
            unsigned int u = *(const unsigned int*)(xs + (size_t)srcn * XPAD + pr * 2);
            float m = (q < cnt) ? 1.f : 0.f;
            a0 = fmaf(m, blo(u), a0);
            a1 = fmaf(m, bhi(u), a1);
        }
    }
    // reduce across the 8 edge slots (lane bits 3,4,5)
    #pragma unroll
    for (int mask = 8; mask <= 32; mask <<= 1) {
        a0 += __shfl_xor(a0, mask);
        a1 += __shfl_xor(a1, mask);
    }
    // self-loop AFTER reduce (each lane adds its own pair exactly once)
    {
        unsigned int us = *(const unsigned int*)(xs + (size_t)row * XPAD + pr * 2);
        a0 += blo(us);
        a1 += bhi(us);
    }
    float d = dis[row];
    // pre[lane] = (xagg @ W1)[lane]; feature k lives on lane (k>>1), elem (k&1)
    float pre = 0.f;
    #pragma unroll
    for (int k = 0; k < INC; ++k) {
        float xv = (k & 1) ? __shfl(a1, k >> 1) : __shfl(a0, k >> 1);
        pre += xv * W1s[k * HID + lane];
    }
    float a = d * pre + b1[lane];
    a = a > 0.f ? a : 0.f;
    arow[wv][lane] = a;                      // wave-internal exchange
    // acc2 = (arow @ W2)[lane] via float4: 16 broadcast + 16 row reads
    const float4* ar4 = (const float4*)&arow[wv][0];
    const float4* wr4 = (const float4*)&W2Ts[lane][0];
    float acc2 = 0.f;
    #pragma unroll
    for (int k4 = 0; k4 < 16; ++k4) {
        float4 av = ar4[k4];
        float4 wv4 = wr4[k4];
        acc2 += av.x * wv4.x + av.y * wv4.y + av.z * wv4.z + av.w * wv4.w;
    }
    g2[(size_t)row * HID + lane] = f2b(d * acc2);
}

// ---- layer-2 aggregation, packed uint4 gather (8 bf16/lane, 8 lanes/edge),
//      fused head. wave per row. ----
__global__ void k_agg2_head(const int* __restrict__ rowptr, const int* __restrict__ csr,
                            const bf16t* __restrict__ g, const float* __restrict__ dis,
                            const float* __restrict__ b2, const float* __restrict__ Wl,
                            const float* __restrict__ bl, float* __restrict__ out, int N) {
    int lane = threadIdx.x & 63;
    int row = (blockIdx.x * blockDim.x + threadIdx.x) >> 6;
    if (row >= N) return;
    int h = lane & 7;        // feature octet: features h*8 .. h*8+7
    int slot = lane >> 3;    // 8 edge slots
    int s = rowptr[row], e = rowptr[row + 1];
    float a0 = 0.f, a1 = 0.f, a2 = 0.f, a3 = 0.f, a4 = 0.f, a5 = 0.f, a6 = 0.f, a7 = 0.f;
    for (int p = s; p < e; p += 64) {
        int idx = (p + lane < e) ? csr[p + lane] : 0;
        int cnt = min(64, e - p);
        for (int j = 0; j * 8 < cnt; ++j) {
            int q = j * 8 + slot;
            int srcn = __shfl(idx, q);          // idx beyond cnt is 0 (safe)
            const uint4 gv = *(const uint4*)(g + (size_t)srcn * HID + h * 8);
            float m = (q < cnt) ? 1.f : 0.f;
            a0 = fmaf(m, blo(gv.x), a0); a1 = fmaf(m, bhi(gv.x), a1);
            a2 = fmaf(m, blo(gv.y), a2); a3 = fmaf(m, bhi(gv.y), a3);
            a4 = fmaf(m, blo(gv.z), a4); a5 = fmaf(m, bhi(gv.z), a5);
            a6 = fmaf(m, blo(gv.w), a6); a7 = fmaf(m, bhi(gv.w), a7);
        }
    }
    // reduce across the 8 edge slots (lane bits 3,4,5)
    #pragma unroll
    for (int mask = 8; mask <= 32; mask <<= 1) {
        a0 += __shfl_xor(a0, mask); a1 += __shfl_xor(a1, mask);
        a2 += __shfl_xor(a2, mask); a3 += __shfl_xor(a3, mask);
        a4 += __shfl_xor(a4, mask); a5 += __shfl_xor(a5, mask);
        a6 += __shfl_xor(a6, mask); a7 += __shfl_xor(a7, mask);
    }
    // self-loop AFTER reduce (each lane adds its own octet exactly once)
    {
        const uint4 gv = *(const uint4*)(g + (size_t)row * HID + h * 8);
        a0 += blo(gv.x); a1 += bhi(gv.x);
        a2 += blo(gv.y); a3 += bhi(gv.y);
        a4 += blo(gv.z); a5 += bhi(gv.z);
        a6 += blo(gv.w); a7 += bhi(gv.w);
    }
    // head: relu(d*acc + b2) . Wl over this lane's 8 features
    float d = dis[row];
    float4 blo4 = *(const float4*)(b2 + h * 8);
    float4 bhi4 = *(const float4*)(b2 + h * 8 + 4);
    float4 wlo4 = *(const float4*)(Wl + h * 8);
    float4 whi4 = *(const float4*)(Wl + h * 8 + 4);
    float part = 0.f;
    float v;
    v = d * a0 + blo4.x; v = v > 0.f ? v : 0.f; part += v * wlo4.x;
    v = d * a1 + blo4.y; v = v > 0.f ? v : 0.f; part += v * wlo4.y;
    v = d * a2 + blo4.z; v = v > 0.f ? v : 0.f; part += v * wlo4.z;
    v = d * a3 + blo4.w; v = v > 0.f ? v : 0.f; part += v * wlo4.w;
    v = d * a4 + bhi4.x; v = v > 0.f ? v : 0.f; part += v * whi4.x;
    v = d * a5 + bhi4.y; v = v > 0.f ? v : 0.f; part += v * whi4.y;
    v = d * a6 + bhi4.z; v = v > 0.f ? v : 0.f; part += v * whi4.z;
    v = d * a7 + bhi4.w; v = v > 0.f ? v : 0.f; part += v * whi4.w;
    // reduce across the 8 octets (lane bits 0,1,2)
    part += __shfl_xor(part, 1);
    part += __shfl_xor(part, 2);
    part += __shfl_xor(part, 4);
    if (lane == 0) out[row] = part + bl[0];
}

extern "C" void kernel_launch(void* const* d_in, const int* in_sizes, int n_in,
                              void* d_out, int out_size, void* d_ws, size_t ws_size,
                              hipStream_t stream) {
    const float* x  = (const float*)d_in[0];
    const int*   ei = (const int*)d_in[1];
    const float* W1 = (const float*)d_in[2];
    const float* b1 = (const float*)d_in[3];
    const float* W2 = (const float*)d_in[4];
    const float* b2 = (const float*)d_in[5];
    const float* Wl = (const float*)d_in[6];
    const float* bl = (const float*)d_in[7];
    float* out = (float*)d_out;

    const int N = in_sizes[0] / INC;    // 100000
    const int E = in_sizes[1] / 2;      // 3200000
    const int NB = (N + BINW - 1) / BINW;        // 782
    const int C  = (E + ECHUNK - 1) / ECHUNK;    // 391
    const int L  = NB * C;                        // 305762
    const int nScan = (L + SCAN_CHUNK - 1) / SCAN_CHUNK;  // 299 (<=512)

    char* ws = (char*)d_ws;
    size_t off = 0;
    auto alloc = [&](size_t bytes) { void* p = ws + off; off += (bytes + 255) / 256 * 256; return p; };
    int*   histT    = (int*)alloc((size_t)L * 4);     // scanned in place
    int*   blocksums= (int*)alloc(512 * 4);
    int*   blockoff = (int*)alloc(512 * 4);
    int*   rowptr   = (int*)alloc((size_t)(N + 1) * 4);
    float* dis      = (float*)alloc((size_t)N * 4);
    int*   csr      = (int*)alloc((size_t)E * 4);
    int*   bucket   = (int*)alloc((size_t)E * 4);
    bf16t* xs       = (bf16t*)alloc((size_t)N * XPAD * 2);   // 3.2 MB
    bf16t* g2       = (bf16t*)alloc((size_t)N * HID * 2);    // 12.8 MB

    const int TPB = 256;
    const int* esrc = ei;
    const int* edst = ei + E;
    const int waveBlocks = ((size_t)N * 64 + TPB - 1) / TPB;

    // CSR build — zero global atomics
    k_hist<<<C, TPB, 0, stream>>>(edst, E, C, NB, histT);
    k_scan1<<<nScan, TPB, 0, stream>>>(histT, L, histT, blocksums);
    k_scan2<<<1, 512, 0, stream>>>(blocksums, nScan, blockoff);
    k_scan3f<<<(L + TPB - 1) / TPB, TPB, 0, stream>>>(histT, blockoff, L);
    k_scatterbin<<<C, TPB, 0, stream>>>(esrc, edst, E, C, NB, histT, bucket);
    k_csrbuild<<<NB, TPB, 0, stream>>>(histT, C, NB, E, bucket, csr, rowptr, dis, N);

    // xs table (needs dis)
    k_xs<<<((N * XPAD) + TPB - 1) / TPB, TPB, 0, stream>>>(x, dis, xs, N);

    // layer 1: packed x-space gather + W1 + relu + vectorized @W2 -> g2 (bf16)
    k_agg1x<<<waveBlocks, TPB, 0, stream>>>(rowptr, csr, xs, dis, W1, b1, W2, g2, N);

    // layer 2: packed-gather aggregation + head
    k_agg2_head<<<waveBlocks, TPB, 0, stream>>>(rowptr, csr, g2, dis, b2, Wl, bl, out, N);
}

// Round 16
// 211.246 us; speedup vs baseline: 20.2682x; 1.0245x over previous
//
#include <hip/hip_runtime.h>

// GCN 2-layer + head.
// R16: agg1x was LDS-pipe-bound (32 ds_read_b128 + ~21 bpermute per row,
//      9.6M bank conflicts). Epilogue evicted:
//      (a) k_agg1x: gather + W1 (readlane broadcasts, off LDS pipe) + relu
//          -> writes a[N][64] bf16; LDS = W1s only (2.8 KB);
//      (b) k_xw2b: dense persistent-block GEMM g2 = bf16(dis*(a@W2)),
//          W2 f32 in LDS (conflict-free), coalesced uint4 bf16 reads;
//      (c) k_agg2_head unchanged (packed uint4 gather, ~fill-floor).
// bucket word = (src<<7) | (dst&127), src < 2^17 fits 24 bits.

#define HID 64
#define INC 11
#define XPAD 16
#define BINSH 7
#define BINW 128
#define MAXNB 800      // >= ceil(100000/128)=782
#define ECHUNK 8192
#define SCAN_CHUNK 1024
#define STAGE_MAX 6144

typedef unsigned short bf16t;

__device__ __forceinline__ float b2f(bf16t u) {
    union { float f; unsigned int i; } v;
    v.i = ((unsigned int)u) << 16;
    return v.f;
}
__device__ __forceinline__ bf16t f2b(float f) {
    union { float ff; unsigned int i; } v;
    v.ff = f;
    unsigned int r = v.i + 0x7FFF + ((v.i >> 16) & 1);   // RNE
    return (bf16t)(r >> 16);
}
__device__ __forceinline__ float blo(unsigned int u) {
    union { float f; unsigned int i; } v; v.i = u << 16; return v.f;
}
__device__ __forceinline__ float bhi(unsigned int u) {
    union { float f; unsigned int i; } v; v.i = u & 0xFFFF0000u; return v.f;
}
__device__ __forceinline__ float rdlane(float v, int l) {
    union { float f; int i; } u; u.f = v;
    u.i = __builtin_amdgcn_readlane(u.i, l);
    return u.f;
}

// ---- per-chunk histogram of dst bins, stored transposed histT[b*C+c] ----
__global__ void k_hist(const int* __restrict__ dst, int E, int C, int NB,
                       int* __restrict__ histT) {
    __shared__ int h[MAXNB];
    int c = blockIdx.x, t = threadIdx.x;
    for (int i = t; i < NB; i += 256) h[i] = 0;
    __syncthreads();
    int base = c * ECHUNK;
    int end = min(base + ECHUNK, E);
    int n4 = (end - base) >> 2;
    const int4* d4 = (const int4*)(dst + base);
    for (int i = t; i < n4; i += 256) {
        int4 d = d4[i];
        atomicAdd(&h[d.x >> BINSH], 1);
        atomicAdd(&h[d.y >> BINSH], 1);
        atomicAdd(&h[d.z >> BINSH], 1);
        atomicAdd(&h[d.w >> BINSH], 1);
    }
    __syncthreads();
    for (int b = t; b < NB; b += 256)
        histT[(size_t)b * C + c] = h[b];
}

// ---- generic 3-kernel exclusive scan (in-place safe), L <= 512*SCAN_CHUNK ----
__global__ void k_scan1(const int* __restrict__ in, int L,
                        int* __restrict__ part, int* __restrict__ blocksums) {
    __shared__ int lds[SCAN_CHUNK];
    __shared__ int tsum[256];
    int b = blockIdx.x, t = threadIdx.x;
    int base = b * SCAN_CHUNK;
    for (int i = t; i < SCAN_CHUNK; i += 256)
        lds[i] = (base + i < L) ? in[base + i] : 0;
    __syncthreads();
    int a0 = lds[t*4], a1 = lds[t*4+1], a2 = lds[t*4+2], a3 = lds[t*4+3];
    int ts = a0 + a1 + a2 + a3;
    tsum[t] = ts;
    __syncthreads();
    for (int off = 1; off < 256; off <<= 1) {
        int v = (t >= off) ? tsum[t - off] : 0;
        __syncthreads();
        tsum[t] += v;
        __syncthreads();
    }
    int excl = tsum[t] - ts;
    int i0 = base + t*4;
    if (i0     < L) part[i0]     = excl;
    if (i0 + 1 < L) part[i0 + 1] = excl + a0;
    if (i0 + 2 < L) part[i0 + 2] = excl + a0 + a1;
    if (i0 + 3 < L) part[i0 + 3] = excl + a0 + a1 + a2;
    if (t == 255) blocksums[b] = tsum[255];
}

__global__ void k_scan2(const int* __restrict__ blocksums, int nb, int* __restrict__ blockoff) {
    __shared__ int s[512];
    int t = threadIdx.x;    // 512 threads
    s[t] = (t < nb) ? blocksums[t] : 0;
    __syncthreads();
    int mine = s[t];
    for (int off = 1; off < 512; off <<= 1) {
        int v = (t >= off) ? s[t - off] : 0;
        __syncthreads();
        s[t] += v;
        __syncthreads();
    }
    blockoff[t] = s[t] - mine;   // exclusive
}

__global__ void k_scan3f(int* __restrict__ part, const int* __restrict__ blockoff, int L) {
    int i = blockIdx.x * blockDim.x + threadIdx.x;
    if (i < L) part[i] += blockoff[i / SCAN_CHUNK];
}

// ---- scatter edges into bin-grouped bucket; rank via LDS atomic, 8 chains ----
__global__ void k_scatterbin(const int* __restrict__ src, const int* __restrict__ dst,
                             int E, int C, int NB, const int* __restrict__ scanT,
                             int* __restrict__ bucket) {
    __shared__ int cur[MAXNB];
    int c = blockIdx.x, t = threadIdx.x;
    for (int b = t; b < NB; b += 256) cur[b] = scanT[(size_t)b * C + c];
    __syncthreads();
    int base = c * ECHUNK;
    int end = min(base + ECHUNK, E);
    int n4 = (end - base) >> 2;
    const int4* d4 = (const int4*)(dst + base);
    const int4* s4 = (const int4*)(src + base);
    for (int i = t; i < n4; i += 512) {
        int4 da = d4[i], sa = s4[i];
        bool hb = (i + 256) < n4;
        int4 db, sb;
        if (hb) { db = d4[i + 256]; sb = s4[i + 256]; }
        int r0 = atomicAdd(&cur[da.x >> BINSH], 1);
        int r1 = atomicAdd(&cur[da.y >> BINSH], 1);
        int r2 = atomicAdd(&cur[da.z >> BINSH], 1);
        int r3 = atomicAdd(&cur[da.w >> BINSH], 1);
        int r4 = 0, r5 = 0, r6 = 0, r7 = 0;
        if (hb) {
            r4 = atomicAdd(&cur[db.x >> BINSH], 1);
            r5 = atomicAdd(&cur[db.y >> BINSH], 1);
            r6 = atomicAdd(&cur[db.z >> BINSH], 1);
            r7 = atomicAdd(&cur[db.w >> BINSH], 1);
        }
        bucket[r0] = (sa.x << BINSH) | (da.x & (BINW - 1));
        bucket[r1] = (sa.y << BINSH) | (da.y & (BINW - 1));
        bucket[r2] = (sa.z << BINSH) | (da.z & (BINW - 1));
        bucket[r3] = (sa.w << BINSH) | (da.w & (BINW - 1));
        if (hb) {
            bucket[r4] = (sb.x << BINSH) | (db.x & (BINW - 1));
            bucket[r5] = (sb.y << BINSH) | (db.y & (BINW - 1));
            bucket[r6] = (sb.z << BINSH) | (db.z & (BINW - 1));
            bucket[r7] = (sb.w << BINSH) | (db.w & (BINW - 1));
        }
    }
}

// ---- per-bin CSR finalize: local degree count, scan, staged coalesced write ----
__global__ void k_csrbuild(const int* __restrict__ scanT, int C, int NB, int E,
                           const int* __restrict__ bucket, int* __restrict__ csr,
                           int* __restrict__ rowptr, float* __restrict__ dis, int N) {
    __shared__ int cnt[BINW];
    __shared__ int ex[BINW];
    __shared__ int cur[BINW];
    __shared__ int stage[STAGE_MAX];
    int b = blockIdx.x, t = threadIdx.x;
    int s = scanT[(size_t)b * C];
    int e = (b + 1 < NB) ? scanT[(size_t)(b + 1) * C] : E;
    int len = e - s;
    if (t < BINW) cnt[t] = 0;
    __syncthreads();
    for (int p = s + t; p < e; p += 256)
        atomicAdd(&cnt[bucket[p] & (BINW - 1)], 1);
    __syncthreads();
    if (t < BINW) ex[t] = cnt[t];
    __syncthreads();
    for (int off = 1; off < BINW; off <<= 1) {
        int v = (t < BINW && t >= off) ? ex[t - off] : 0;
        __syncthreads();
        if (t < BINW) ex[t] += v;
        __syncthreads();
    }
    if (t < BINW) {
        int excl = ex[t] - cnt[t];
        cur[t] = excl;
        int n = b * BINW + t;
        if (n <= N) rowptr[n] = s + excl;
        if (n < N)  dis[n] = rsqrtf((float)(cnt[t] + 1));
    }
    __syncthreads();
    if (len <= STAGE_MAX) {
        for (int p = s + t; p < e; p += 256) {
            int w = bucket[p];
            int r = atomicAdd(&cur[w & (BINW - 1)], 1);
            stage[r] = w >> BINSH;
        }
        __syncthreads();
        for (int i = t; i < len; i += 256) csr[s + i] = stage[i];
    } else {
        for (int p = s + t; p < e; p += 256) {
            int w = bucket[p];
            int r = atomicAdd(&cur[w & (BINW - 1)], 1);
            csr[s + r] = w >> BINSH;
        }
    }
}

// ---- xs[N][16] = bf16(dis[row] * x[row][0..10]), padded with zeros ----
__global__ void k_xs(const float* __restrict__ x, const float* __restrict__ dis,
                     bf16t* __restrict__ xs, int N) {
    int i = blockIdx.x * blockDim.x + threadIdx.x;
    if (i < N * XPAD) {
        int row = i >> 4, f = i & 15;
        float v = (f < INC) ? dis[row] * x[row * INC + f] : 0.f;
        xs[i] = f2b(v);
    }
}

// ---- layer-1: packed x-space gather + W1 (readlane) + relu -> a[N][64] bf16 ----
// gather: lane = (slot = l>>3 of 8 edges, pair = l&7 -> features 2p, 2p+1).
__global__ void k_agg1x(const int* __restrict__ rowptr, const int* __restrict__ csr,
                        const bf16t* __restrict__ xs, const float* __restrict__ dis,
                        const float* __restrict__ W1, const float* __restrict__ b1,
                        bf16t* __restrict__ a_out, int N) {
    __shared__ float W1s[INC * HID];   // 2.75 KB (only LDS in kernel)
    int t = threadIdx.x;
    for (int i = t; i < INC * HID; i += 256) W1s[i] = W1[i];
    __syncthreads();
    int lane = t & 63;
    int row = (blockIdx.x * blockDim.x + t) >> 6;
    if (row >= N) return;
    int pr = lane & 7;       // feature pair: features 2*pr, 2*pr+1
    int slot = lane >> 3;    // 8 edge slots
    int p0 = rowptr[row], p1 = rowptr[row + 1];
    float a0 = 0.f, a1 = 0.f;
    for (int p = p0; p < p1; p += 64) {
        int idx = (p + lane < p1) ? csr[p + lane] : 0;
        int cnt = min(64, p1 - p);
        for (int j = 0; j * 8 < cnt; ++j) {
            int q = j * 8 + slot;
            int srcn = __shfl(idx, q);       // idx beyond cnt is 0 (safe addr)
            unsigned int u = *(const unsigned int*)(xs + (size_t)srcn * XPAD + pr * 2);
            float m = (q < cnt) ? 1.f : 0.f;
            a0 = fmaf(m, blo(u), a0);
            a1 = fmaf(m, bhi(u), a1);
        }
    }
    // reduce across the 8 edge slots (lane bits 3,4,5)
    #pragma unroll
    for (int mask = 8; mask <= 32; mask <<= 1) {
        a0 += __shfl_xor(a0, mask);
        a1 += __shfl_xor(a1, mask);
    }
    // self-loop AFTER reduce (each lane adds its own pair exactly once)
    {
        unsigned int us = *(const unsigned int*)(xs + (size_t)row * XPAD + pr * 2);
        a0 += blo(us);
        a1 += bhi(us);
    }
    float d = dis[row];
    // pre[lane] = (xagg @ W1)[lane]; feature k on lane (k>>1), elem (k&1).
    // readlane broadcast (SALU/VALU path — off the LDS pipe).
    float pre = 0.f;
    #pragma unroll
    for (int k = 0; k < INC; ++k) {
        float xv = (k & 1) ? rdlane(a1, k >> 1) : rdlane(a0, k >> 1);
        pre += xv * W1s[k * HID + lane];
    }
    float a = d * pre + b1[lane];
    a = a > 0.f ? a : 0.f;
    a_out[(size_t)row * HID + lane] = f2b(a);
}

// ---- dense GEMM: g2[row][c] = bf16(dis[row] * (a[row] @ W2)[c]) ----
// persistent blocks, W2 f32 in LDS (lane-consecutive reads: conflict-free).
__global__ void k_xw2b(const bf16t* __restrict__ a, const float* __restrict__ W2,
                       const float* __restrict__ dis, bf16t* __restrict__ g2, int N) {
    __shared__ float Ws[HID * HID];   // 16 KB
    int t = threadIdx.x;
    for (int i = t; i < HID * HID; i += 256) Ws[i] = W2[i];
    __syncthreads();
    int c = t & 63;
    for (int row = blockIdx.x * 4 + (t >> 6); row < N; row += gridDim.x * 4) {
        const uint4* r4 = (const uint4*)(a + (size_t)row * HID);
        float acc = 0.f;
        #pragma unroll
        for (int q = 0; q < 8; ++q) {
            uint4 u = r4[q];
            int k = q * 8;
            acc += blo(u.x) * Ws[(k    ) * HID + c];
            acc += bhi(u.x) * Ws[(k + 1) * HID + c];
            acc += blo(u.y) * Ws[(k + 2) * HID + c];
            acc += bhi(u.y) * Ws[(k + 3) * HID + c];
            acc += blo(u.z) * Ws[(k + 4) * HID + c];
            acc += bhi(u.z) * Ws[(k + 5) * HID + c];
            acc += blo(u.w) * Ws[(k + 6) * HID + c];
            acc += bhi(u.w) * Ws[(k + 7) * HID + c];
        }
        g2[(size_t)row * HID + c] = f2b(dis[row] * acc);
    }
}

// ---- layer-2 aggregation, packed uint4 gather (8 bf16/lane, 8 lanes/edge),
//      fused head. wave per row. ----
__global__ void k_agg2_head(const int* __restrict__ rowptr, const int* __restrict__ csr,
                            const bf16t* __restrict__ g, const float* __restrict__ dis,
                            const float* __restrict__ b2, const float* __restrict__ Wl,
                            const float* __restrict__ bl, float* __restrict__ out, int N) {
    int lane = threadIdx.x & 63;
    int row = (blockIdx.x * blockDim.x + threadIdx.x) >> 6;
    if (row >= N) return;
    int h = lane & 7;        // feature octet: features h*8 .. h*8+7
    int slot = lane >> 3;    // 8 edge slots
    int s = rowptr[row], e = rowptr[row + 1];
    float a0 = 0.f, a1 = 0.f, a2 = 0.f, a3 = 0.f, a4 = 0.f, a5 = 0.f, a6 = 0.f, a7 = 0.f;
    for (int p = s; p < e; p += 64) {
        int idx = (p + lane < e) ? csr[p + lane] : 0;
        int cnt = min(64, e - p);
        for (int j = 0; j * 8 < cnt; ++j) {
            int q = j * 8 + slot;
            int srcn = __shfl(idx, q);          // idx beyond cnt is 0 (safe)
            const uint4 gv = *(const uint4*)(g + (size_t)srcn * HID + h * 8);
            float m = (q < cnt) ? 1.f : 0.f;
            a0 = fmaf(m, blo(gv.x), a0); a1 = fmaf(m, bhi(gv.x), a1);
            a2 = fmaf(m, blo(gv.y), a2); a3 = fmaf(m, bhi(gv.y), a3);
            a4 = fmaf(m, blo(gv.z), a4); a5 = fmaf(m, bhi(gv.z), a5);
            a6 = fmaf(m, blo(gv.w), a6); a7 = fmaf(m, bhi(gv.w), a7);
        }
    }
    // reduce across the 8 edge slots (lane bits 3,4,5)
    #pragma unroll
    for (int mask = 8; mask <= 32; mask <<= 1) {
        a0 += __shfl_xor(a0, mask); a1 += __shfl_xor(a1, mask);
        a2 += __shfl_xor(a2, mask); a3 += __shfl_xor(a3, mask);
        a4 += __shfl_xor(a4, mask); a5 += __shfl_xor(a5, mask);
        a6 += __shfl_xor(a6, mask); a7 += __shfl_xor(a7, mask);
    }
    // self-loop AFTER reduce (each lane adds its own octet exactly once)
    {
        const uint4 gv = *(const uint4*)(g + (size_t)row * HID + h * 8);
        a0 += blo(gv.x); a1 += bhi(gv.x);
        a2 += blo(gv.y); a3 += bhi(gv.y);
        a4 += blo(gv.z); a5 += bhi(gv.z);
        a6 += blo(gv.w); a7 += bhi(gv.w);
    }
    // head: relu(d*acc + b2) . Wl over this lane's 8 features
    float d = dis[row];
    float4 blo4 = *(const float4*)(b2 + h * 8);
    float4 bhi4 = *(const float4*)(b2 + h * 8 + 4);
    float4 wlo4 = *(const float4*)(Wl + h * 8);
    float4 whi4 = *(const float4*)(Wl + h * 8 + 4);
    float part = 0.f;
    float v;
    v = d * a0 + blo4.x; v = v > 0.f ? v : 0.f; part += v * wlo4.x;
    v = d * a1 + blo4.y; v = v > 0.f ? v : 0.f; part += v * wlo4.y;
    v = d * a2 + blo4.z; v = v > 0.f ? v : 0.f; part += v * wlo4.z;
    v = d * a3 + blo4.w; v = v > 0.f ? v : 0.f; part += v * wlo4.w;
    v = d * a4 + bhi4.x; v = v > 0.f ? v : 0.f; part += v * whi4.x;
    v = d * a5 + bhi4.y; v = v > 0.f ? v : 0.f; part += v * whi4.y;
    v = d * a6 + bhi4.z; v = v > 0.f ? v : 0.f; part += v * whi4.z;
    v = d * a7 + bhi4.w; v = v > 0.f ? v : 0.f; part += v * whi4.w;
    // reduce across the 8 octets (lane bits 0,1,2)
    part += __shfl_xor(part, 1);
    part += __shfl_xor(part, 2);
    part += __shfl_xor(part, 4);
    if (lane == 0) out[row] = part + bl[0];
}

extern "C" void kernel_launch(void* const* d_in, const int* in_sizes, int n_in,
                              void* d_out, int out_size, void* d_ws, size_t ws_size,
                              hipStream_t stream) {
    const float* x  = (const float*)d_in[0];
    const int*   ei = (const int*)d_in[1];
    const float* W1 = (const float*)d_in[2];
    const float* b1 = (const float*)d_in[3];
    const float* W2 = (const float*)d_in[4];
    const float* b2 = (const float*)d_in[5];
    const float* Wl = (const float*)d_in[6];
    const float* bl = (const float*)d_in[7];
    float* out = (float*)d_out;

    const int N = in_sizes[0] / INC;    // 100000
    const int E = in_sizes[1] / 2;      // 3200000
    const int NB = (N + BINW - 1) / BINW;        // 782
    const int C  = (E + ECHUNK - 1) / ECHUNK;    // 391
    const int L  = NB * C;                        // 305762
    const int nScan = (L + SCAN_CHUNK - 1) / SCAN_CHUNK;  // 299 (<=512)

    char* ws = (char*)d_ws;
    size_t off = 0;
    auto alloc = [&](size_t bytes) { void* p = ws + off; off += (bytes + 255) / 256 * 256; return p; };
    int*   histT    = (int*)alloc((size_t)L * 4);     // scanned in place
    int*   blocksums= (int*)alloc(512 * 4);
    int*   blockoff = (int*)alloc(512 * 4);
    int*   rowptr   = (int*)alloc((size_t)(N + 1) * 4);
    float* dis      = (float*)alloc((size_t)N * 4);
    int*   csr      = (int*)alloc((size_t)E * 4);
    int*   bucket   = (int*)alloc((size_t)E * 4);
    bf16t* xs       = (bf16t*)alloc((size_t)N * XPAD * 2);   // 3.2 MB
    bf16t* a_bf     = (bf16t*)alloc((size_t)N * HID * 2);    // 12.8 MB
    bf16t* g2       = (bf16t*)alloc((size_t)N * HID * 2);    // 12.8 MB

    const int TPB = 256;
    const int* esrc = ei;
    const int* edst = ei + E;
    const int waveBlocks = ((size_t)N * 64 + TPB - 1) / TPB;

    // CSR build — zero global atomics
    k_hist<<<C, TPB, 0, stream>>>(edst, E, C, NB, histT);
    k_scan1<<<nScan, TPB, 0, stream>>>(histT, L, histT, blocksums);
    k_scan2<<<1, 512, 0, stream>>>(blocksums, nScan, blockoff);
    k_scan3f<<<(L + TPB - 1) / TPB, TPB, 0, stream>>>(histT, blockoff, L);
    k_scatterbin<<<C, TPB, 0, stream>>>(esrc, edst, E, C, NB, histT, bucket);
    k_csrbuild<<<NB, TPB, 0, stream>>>(histT, C, NB, E, bucket, csr, rowptr, dis, N);

    // xs table (needs dis)
    k_xs<<<((N * XPAD) + TPB - 1) / TPB, TPB, 0, stream>>>(x, dis, xs, N);

    // layer 1: x-space gather + W1 + relu -> a (bf16)
    k_agg1x<<<waveBlocks, TPB, 0, stream>>>(rowptr, csr, xs, dis, W1, b1, a_bf, N);

    // dense a@W2 -> g2 (bf16)
    k_xw2b<<<2048, TPB, 0, stream>>>(a_bf, W2, dis, g2, N);

    // layer 2: packed-gather aggregation + head
    k_agg2_head<<<waveBlocks, TPB, 0, stream>>>(rowptr, csr, g2, dis, b2, Wl, bl, out, N);
}

// Round 18
// 201.345 us; speedup vs baseline: 21.2649x; 1.0492x over previous
//
#include <hip/hip_runtime.h>

// GCN 2-layer + head.
// R18: R17 with the divergent-tail shfl bug fixed. On CDNA, __shfl =
//      ds_bpermute and EXEC gates SOURCE reads: reading idx from a lane
//      that is masked off by `if (q < cnt)` returns undefined data (the
//      source lanes 56..63 are exactly the ones inactive in the tail).
//      Fix: execute the shfl with ALL lanes active (index clamped), only
//      the load+add sits inside the divergent branch.
//      Retained from R17: MLP-unrolled full groups (2 loads in flight),
//      512-thread hist/scatterbin.
// bucket word = (src<<7) | (dst&127), src < 2^17 fits 24 bits.

#define HID 64
#define INC 11
#define XPAD 16
#define BINSH 7
#define BINW 128
#define MAXNB 800      // >= ceil(100000/128)=782
#define ECHUNK 8192
#define SCAN_CHUNK 1024
#define STAGE_MAX 6144

typedef unsigned short bf16t;

__device__ __forceinline__ float b2f(bf16t u) {
    union { float f; unsigned int i; } v;
    v.i = ((unsigned int)u) << 16;
    return v.f;
}
__device__ __forceinline__ bf16t f2b(float f) {
    union { float ff; unsigned int i; } v;
    v.ff = f;
    unsigned int r = v.i + 0x7FFF + ((v.i >> 16) & 1);   // RNE
    return (bf16t)(r >> 16);
}
__device__ __forceinline__ float blo(unsigned int u) {
    union { float f; unsigned int i; } v; v.i = u << 16; return v.f;
}
__device__ __forceinline__ float bhi(unsigned int u) {
    union { float f; unsigned int i; } v; v.i = u & 0xFFFF0000u; return v.f;
}
__device__ __forceinline__ float rdlane(float v, int l) {
    union { float f; int i; } u; u.f = v;
    u.i = __builtin_amdgcn_readlane(u.i, l);
    return u.f;
}

// ---- per-chunk histogram of dst bins, stored transposed histT[b*C+c] ----
__global__ void k_hist(const int* __restrict__ dst, int E, int C, int NB,
                       int* __restrict__ histT) {
    __shared__ int h[MAXNB];
    int c = blockIdx.x, t = threadIdx.x;    // 512 threads
    for (int i = t; i < NB; i += 512) h[i] = 0;
    __syncthreads();
    int base = c * ECHUNK;
    int end = min(base + ECHUNK, E);
    int n4 = (end - base) >> 2;
    const int4* d4 = (const int4*)(dst + base);
    for (int i = t; i < n4; i += 512) {
        int4 d = d4[i];
        atomicAdd(&h[d.x >> BINSH], 1);
        atomicAdd(&h[d.y >> BINSH], 1);
        atomicAdd(&h[d.z >> BINSH], 1);
        atomicAdd(&h[d.w >> BINSH], 1);
    }
    __syncthreads();
    for (int b = t; b < NB; b += 512)
        histT[(size_t)b * C + c] = h[b];
}

// ---- generic 3-kernel exclusive scan (in-place safe), L <= 512*SCAN_CHUNK ----
__global__ void k_scan1(const int* __restrict__ in, int L,
                        int* __restrict__ part, int* __restrict__ blocksums) {
    __shared__ int lds[SCAN_CHUNK];
    __shared__ int tsum[256];
    int b = blockIdx.x, t = threadIdx.x;
    int base = b * SCAN_CHUNK;
    for (int i = t; i < SCAN_CHUNK; i += 256)
        lds[i] = (base + i < L) ? in[base + i] : 0;
    __syncthreads();
    int a0 = lds[t*4], a1 = lds[t*4+1], a2 = lds[t*4+2], a3 = lds[t*4+3];
    int ts = a0 + a1 + a2 + a3;
    tsum[t] = ts;
    __syncthreads();
    for (int off = 1; off < 256; off <<= 1) {
        int v = (t >= off) ? tsum[t - off] : 0;
        __syncthreads();
        tsum[t] += v;
        __syncthreads();
    }
    int excl = tsum[t] - ts;
    int i0 = base + t*4;
    if (i0     < L) part[i0]     = excl;
    if (i0 + 1 < L) part[i0 + 1] = excl + a0;
    if (i0 + 2 < L) part[i0 + 2] = excl + a0 + a1;
    if (i0 + 3 < L) part[i0 + 3] = excl + a0 + a1 + a2;
    if (t == 255) blocksums[b] = tsum[255];
}

__global__ void k_scan2(const int* __restrict__ blocksums, int nb, int* __restrict__ blockoff) {
    __shared__ int s[512];
    int t = threadIdx.x;    // 512 threads
    s[t] = (t < nb) ? blocksums[t] : 0;
    __syncthreads();
    int mine = s[t];
    for (int off = 1; off < 512; off <<= 1) {
        int v = (t >= off) ? s[t - off] : 0;
        __syncthreads();
        s[t] += v;
        __syncthreads();
    }
    blockoff[t] = s[t] - mine;   // exclusive
}

__global__ void k_scan3f(int* __restrict__ part, const int* __restrict__ blockoff, int L) {
    int i = blockIdx.x * blockDim.x + threadIdx.x;
    if (i < L) part[i] += blockoff[i / SCAN_CHUNK];
}

// ---- scatter edges into bin-grouped bucket; rank via LDS atomic, 8 chains ----
__global__ void k_scatterbin(const int* __restrict__ src, const int* __restrict__ dst,
                             int E, int C, int NB, const int* __restrict__ scanT,
                             int* __restrict__ bucket) {
    __shared__ int cur[MAXNB];
    int c = blockIdx.x, t = threadIdx.x;    // 512 threads
    for (int b = t; b < NB; b += 512) cur[b] = scanT[(size_t)b * C + c];
    __syncthreads();
    int base = c * ECHUNK;
    int end = min(base + ECHUNK, E);
    int n4 = (end - base) >> 2;
    const int4* d4 = (const int4*)(dst + base);
    const int4* s4 = (const int4*)(src + base);
    for (int i = t; i < n4; i += 1024) {
        int4 da = d4[i], sa = s4[i];
        bool hb = (i + 512) < n4;
        int4 db, sb;
        if (hb) { db = d4[i + 512]; sb = s4[i + 512]; }
        int r0 = atomicAdd(&cur[da.x >> BINSH], 1);
        int r1 = atomicAdd(&cur[da.y >> BINSH], 1);
        int r2 = atomicAdd(&cur[da.z >> BINSH], 1);
        int r3 = atomicAdd(&cur[da.w >> BINSH], 1);
        int r4 = 0, r5 = 0, r6 = 0, r7 = 0;
        if (hb) {
            r4 = atomicAdd(&cur[db.x >> BINSH], 1);
            r5 = atomicAdd(&cur[db.y >> BINSH], 1);
            r6 = atomicAdd(&cur[db.z >> BINSH], 1);
            r7 = atomicAdd(&cur[db.w >> BINSH], 1);
        }
        bucket[r0] = (sa.x << BINSH) | (da.x & (BINW - 1));
        bucket[r1] = (sa.y << BINSH) | (da.y & (BINW - 1));
        bucket[r2] = (sa.z << BINSH) | (da.z & (BINW - 1));
        bucket[r3] = (sa.w << BINSH) | (da.w & (BINW - 1));
        if (hb) {
            bucket[r4] = (sb.x << BINSH) | (db.x & (BINW - 1));
            bucket[r5] = (sb.y << BINSH) | (db.y & (BINW - 1));
            bucket[r6] = (sb.z << BINSH) | (db.z & (BINW - 1));
            bucket[r7] = (sb.w << BINSH) | (db.w & (BINW - 1));
        }
    }
}

// ---- per-bin CSR finalize: local degree count, scan, staged coalesced write ----
__global__ void k_csrbuild(const int* __restrict__ scanT, int C, int NB, int E,
                           const int* __restrict__ bucket, int* __restrict__ csr,
                           int* __restrict__ rowptr, float* __restrict__ dis, int N) {
    __shared__ int cnt[BINW];
    __shared__ int ex[BINW];
    __shared__ int cur[BINW];
    __shared__ int stage[STAGE_MAX];
    int b = blockIdx.x, t = threadIdx.x;
    int s = scanT[(size_t)b * C];
    int e = (b + 1 < NB) ? scanT[(size_t)(b + 1) * C] : E;
    int len = e - s;
    if (t < BINW) cnt[t] = 0;
    __syncthreads();
    for (int p = s + t; p < e; p += 256)
        atomicAdd(&cnt[bucket[p] & (BINW - 1)], 1);
    __syncthreads();
    if (t < BINW) ex[t] = cnt[t];
    __syncthreads();
    for (int off = 1; off < BINW; off <<= 1) {
        int v = (t < BINW && t >= off) ? ex[t - off] : 0;
        __syncthreads();
        if (t < BINW) ex[t] += v;
        __syncthreads();
    }
    if (t < BINW) {
        int excl = ex[t] - cnt[t];
        cur[t] = excl;
        int n = b * BINW + t;
        if (n <= N) rowptr[n] = s + excl;
        if (n < N)  dis[n] = rsqrtf((float)(cnt[t] + 1));
    }
    __syncthreads();
    if (len <= STAGE_MAX) {
        for (int p = s + t; p < e; p += 256) {
            int w = bucket[p];
            int r = atomicAdd(&cur[w & (BINW - 1)], 1);
            stage[r] = w >> BINSH;
        }
        __syncthreads();
        for (int i = t; i < len; i += 256) csr[s + i] = stage[i];
    } else {
        for (int p = s + t; p < e; p += 256) {
            int w = bucket[p];
            int r = atomicAdd(&cur[w & (BINW - 1)], 1);
            csr[s + r] = w >> BINSH;
        }
    }
}

// ---- xs[N][16] = bf16(dis[row] * x[row][0..10]), padded with zeros ----
__global__ void k_xs(const float* __restrict__ x, const float* __restrict__ dis,
                     bf16t* __restrict__ xs, int N) {
    int i = blockIdx.x * blockDim.x + threadIdx.x;
    if (i < N * XPAD) {
        int row = i >> 4, f = i & 15;
        float v = (f < INC) ? dis[row] * x[row * INC + f] : 0.f;
        xs[i] = f2b(v);
    }
}

// ---- layer-1: packed x-space gather + W1 (readlane) + relu -> a[N][64] bf16 ----
// gather: lane = (slot = l>>3 of 8 edges, pair = l&7 -> features 2p, 2p+1).
__global__ void k_agg1x(const int* __restrict__ rowptr, const int* __restrict__ csr,
                        const bf16t* __restrict__ xs, const float* __restrict__ dis,
                        const float* __restrict__ W1, const float* __restrict__ b1,
                        bf16t* __restrict__ a_out, int N) {
    __shared__ float W1s[INC * HID];   // 2.75 KB (only LDS in kernel)
    int t = threadIdx.x;
    for (int i = t; i < INC * HID; i += 256) W1s[i] = W1[i];
    __syncthreads();
    int lane = t & 63;
    int row = (blockIdx.x * blockDim.x + t) >> 6;
    if (row >= N) return;
    int pr = lane & 7;       // feature pair: features 2*pr, 2*pr+1
    int slot = lane >> 3;    // 8 edge slots
    int p0 = rowptr[row], p1 = rowptr[row + 1];
    float a0 = 0.f, a1 = 0.f;
    for (int p = p0; p < p1; p += 64) {
        int idx = (p + lane < p1) ? csr[p + lane] : 0;
        int cnt = min(64, p1 - p);
        int nfull = cnt >> 3;            // wave-uniform -> no divergence
        int j = 0;
        for (; j + 2 <= nfull; j += 2) { // 2 independent loads in flight
            int sA = __shfl(idx, j * 8 + slot);
            int sB = __shfl(idx, j * 8 + 8 + slot);
            unsigned int uA = *(const unsigned int*)(xs + (size_t)sA * XPAD + pr * 2);
            unsigned int uB = *(const unsigned int*)(xs + (size_t)sB * XPAD + pr * 2);
            a0 += blo(uA); a1 += bhi(uA);
            a0 += blo(uB); a1 += bhi(uB);
        }
        for (; j < nfull; ++j) {
            int sA = __shfl(idx, j * 8 + slot);
            unsigned int uA = *(const unsigned int*)(xs + (size_t)sA * XPAD + pr * 2);
            a0 += blo(uA); a1 += bhi(uA);
        }
        // tail: shfl executed by ALL lanes (bpermute reads require active
        // source lanes); only the load+add is divergent.
        int q = nfull * 8 + slot;
        int sA = __shfl(idx, q & 63);
        if (q < cnt) {
            unsigned int uA = *(const unsigned int*)(xs + (size_t)sA * XPAD + pr * 2);
            a0 += blo(uA); a1 += bhi(uA);
        }
    }
    // reduce across the 8 edge slots (lane bits 3,4,5)
    #pragma unroll
    for (int mask = 8; mask <= 32; mask <<= 1) {
        a0 += __shfl_xor(a0, mask);
        a1 += __shfl_xor(a1, mask);
    }
    // self-loop AFTER reduce (each lane adds its own pair exactly once)
    {
        unsigned int us = *(const unsigned int*)(xs + (size_t)row * XPAD + pr * 2);
        a0 += blo(us);
        a1 += bhi(us);
    }
    float d = dis[row];
    // pre[lane] = (xagg @ W1)[lane]; feature k on lane (k>>1), elem (k&1).
    float pre = 0.f;
    #pragma unroll
    for (int k = 0; k < INC; ++k) {
        float xv = (k & 1) ? rdlane(a1, k >> 1) : rdlane(a0, k >> 1);
        pre += xv * W1s[k * HID + lane];
    }
    float a = d * pre + b1[lane];
    a = a > 0.f ? a : 0.f;
    a_out[(size_t)row * HID + lane] = f2b(a);
}

// ---- dense GEMM: g2[row][c] = bf16(dis[row] * (a[row] @ W2)[c]) ----
__global__ void k_xw2b(const bf16t* __restrict__ a, const float* __restrict__ W2,
                       const float* __restrict__ dis, bf16t* __restrict__ g2, int N) {
    __shared__ float Ws[HID * HID];   // 16 KB
    int t = threadIdx.x;
    for (int i = t; i < HID * HID; i += 256) Ws[i] = W2[i];
    __syncthreads();
    int c = t & 63;
    for (int row = blockIdx.x * 4 + (t >> 6); row < N; row += gridDim.x * 4) {
        const uint4* r4 = (const uint4*)(a + (size_t)row * HID);
        float acc = 0.f;
        #pragma unroll
        for (int q = 0; q < 8; ++q) {
            uint4 u = r4[q];
            int k = q * 8;
            acc += blo(u.x) * Ws[(k    ) * HID + c];
            acc += bhi(u.x) * Ws[(k + 1) * HID + c];
            acc += blo(u.y) * Ws[(k + 2) * HID + c];
            acc += bhi(u.y) * Ws[(k + 3) * HID + c];
            acc += blo(u.z) * Ws[(k + 4) * HID + c];
            acc += bhi(u.z) * Ws[(k + 5) * HID + c];
            acc += blo(u.w) * Ws[(k + 6) * HID + c];
            acc += bhi(u.w) * Ws[(k + 7) * HID + c];
        }
        g2[(size_t)row * HID + c] = f2b(dis[row] * acc);
    }
}

// ---- layer-2 aggregation, packed uint4 gather (8 bf16/lane, 8 lanes/edge),
//      full groups unrolled x2, all-lane tail shfl; fused head. wave/row. ----
__global__ void k_agg2_head(const int* __restrict__ rowptr, const int* __restrict__ csr,
                            const bf16t* __restrict__ g, const float* __restrict__ dis,
                            const float* __restrict__ b2, const float* __restrict__ Wl,
                            const float* __restrict__ bl, float* __restrict__ out, int N) {
    int lane = threadIdx.x & 63;
    int row = (blockIdx.x * blockDim.x + threadIdx.x) >> 6;
    if (row >= N) return;
    int h = lane & 7;        // feature octet: features h*8 .. h*8+7
    int slot = lane >> 3;    // 8 edge slots
    int s = rowptr[row], e = rowptr[row + 1];
    float a0 = 0.f, a1 = 0.f, a2 = 0.f, a3 = 0.f, a4 = 0.f, a5 = 0.f, a6 = 0.f, a7 = 0.f;
    for (int p = s; p < e; p += 64) {
        int idx = (p + lane < e) ? csr[p + lane] : 0;
        int cnt = min(64, e - p);
        int nfull = cnt >> 3;              // wave-uniform
        int j = 0;
        for (; j + 2 <= nfull; j += 2) {   // 2 independent loads in flight
            int sA = __shfl(idx, j * 8 + slot);
            int sB = __shfl(idx, j * 8 + 8 + slot);
            const uint4 vA = *(const uint4*)(g + (size_t)sA * HID + h * 8);
            const uint4 vB = *(const uint4*)(g + (size_t)sB * HID + h * 8);
            a0 += blo(vA.x); a1 += bhi(vA.x);
            a2 += blo(vA.y); a3 += bhi(vA.y);
            a4 += blo(vA.z); a5 += bhi(vA.z);
            a6 += blo(vA.w); a7 += bhi(vA.w);
            a0 += blo(vB.x); a1 += bhi(vB.x);
            a2 += blo(vB.y); a3 += bhi(vB.y);
            a4 += blo(vB.z); a5 += bhi(vB.z);
            a6 += blo(vB.w); a7 += bhi(vB.w);
        }
        for (; j < nfull; ++j) {
            int sA = __shfl(idx, j * 8 + slot);
            const uint4 vA = *(const uint4*)(g + (size_t)sA * HID + h * 8);
            a0 += blo(vA.x); a1 += bhi(vA.x);
            a2 += blo(vA.y); a3 += bhi(vA.y);
            a4 += blo(vA.z); a5 += bhi(vA.z);
            a6 += blo(vA.w); a7 += bhi(vA.w);
        }
        // tail: shfl by ALL lanes, divergent load+add only
        int q = nfull * 8 + slot;
        int sA = __shfl(idx, q & 63);
        if (q < cnt) {
            const uint4 vA = *(const uint4*)(g + (size_t)sA * HID + h * 8);
            a0 += blo(vA.x); a1 += bhi(vA.x);
            a2 += blo(vA.y); a3 += bhi(vA.y);
            a4 += blo(vA.z); a5 += bhi(vA.z);
            a6 += blo(vA.w); a7 += bhi(vA.w);
        }
    }
    // reduce across the 8 edge slots (lane bits 3,4,5)
    #pragma unroll
    for (int mask = 8; mask <= 32; mask <<= 1) {
        a0 += __shfl_xor(a0, mask); a1 += __shfl_xor(a1, mask);
        a2 += __shfl_xor(a2, mask); a3 += __shfl_xor(a3, mask);
        a4 += __shfl_xor(a4, mask); a5 += __shfl_xor(a5, mask);
        a6 += __shfl_xor(a6, mask); a7 += __shfl_xor(a7, mask);
    }
    // self-loop AFTER reduce (each lane adds its own octet exactly once)
    {
        const uint4 gv = *(const uint4*)(g + (size_t)row * HID + h * 8);
        a0 += blo(gv.x); a1 += bhi(gv.x);
        a2 += blo(gv.y); a3 += bhi(gv.y);
        a4 += blo(gv.z); a5 += bhi(gv.z);
        a6 += blo(gv.w); a7 += bhi(gv.w);
    }
    // head: relu(d*acc + b2) . Wl over this lane's 8 features
    float d = dis[row];
    float4 blo4 = *(const float4*)(b2 + h * 8);
    float4 bhi4 = *(const float4*)(b2 + h * 8 + 4);
    float4 wlo4 = *(const float4*)(Wl + h * 8);
    float4 whi4 = *(const float4*)(Wl + h * 8 + 4);
    float part = 0.f;
    float v;
    v = d * a0 + blo4.x; v = v > 0.f ? v : 0.f; part += v * wlo4.x;
    v = d * a1 + blo4.y; v = v > 0.f ? v : 0.f; part += v * wlo4.y;
    v = d * a2 + blo4.z; v = v > 0.f ? v : 0.f; part += v * wlo4.z;
    v = d * a3 + blo4.w; v = v > 0.f ? v : 0.f; part += v * wlo4.w;
    v = d * a4 + bhi4.x; v = v > 0.f ? v : 0.f; part += v * whi4.x;
    v = d * a5 + bhi4.y; v = v > 0.f ? v : 0.f; part += v * whi4.y;
    v = d * a6 + bhi4.z; v = v > 0.f ? v : 0.f; part += v * whi4.z;
    v = d * a7 + bhi4.w; v = v > 0.f ? v : 0.f; part += v * whi4.w;
    // reduce across the 8 octets (lane bits 0,1,2)
    part += __shfl_xor(part, 1);
    part += __shfl_xor(part, 2);
    part += __shfl_xor(part, 4);
    if (lane == 0) out[row] = part + bl[0];
}

extern "C" void kernel_launch(void* const* d_in, const int* in_sizes, int n_in,
                              void* d_out, int out_size, void* d_ws, size_t ws_size,
                              hipStream_t stream) {
    const float* x  = (const float*)d_in[0];
    const int*   ei = (const int*)d_in[1];
    const float* W1 = (const float*)d_in[2];
    const float* b1 = (const float*)d_in[3];
    const float* W2 = (const float*)d_in[4];
    const float* b2 = (const float*)d_in[5];
    const float* Wl = (const float*)d_in[6];
    const float* bl = (const float*)d_in[7];
    float* out = (float*)d_out;

    const int N = in_sizes[0] / INC;    // 100000
    const int E = in_sizes[1] / 2;      // 3200000
    const int NB = (N + BINW - 1) / BINW;        // 782
    const int C  = (E + ECHUNK - 1) / ECHUNK;    // 391
    const int L  = NB * C;                        // 305762
    const int nScan = (L + SCAN_CHUNK - 1) / SCAN_CHUNK;  // 299 (<=512)

    char* ws = (char*)d_ws;
    size_t off = 0;
    auto alloc = [&](size_t bytes) { void* p = ws + off; off += (bytes + 255) / 256 * 256; return p; };
    int*   histT    = (int*)alloc((size_t)L * 4);     // scanned in place
    int*   blocksums= (int*)alloc(512 * 4);
    int*   blockoff = (int*)alloc(512 * 4);
    int*   rowptr   = (int*)alloc((size_t)(N + 1) * 4);
    float* dis      = (float*)alloc((size_t)N * 4);
    int*   csr      = (int*)alloc((size_t)E * 4);
    int*   bucket   = (int*)alloc((size_t)E * 4);
    bf16t* xs       = (bf16t*)alloc((size_t)N * XPAD * 2);   // 3.2 MB
    bf16t* a_bf     = (bf16t*)alloc((size_t)N * HID * 2);    // 12.8 MB
    bf16t* g2       = (bf16t*)alloc((size_t)N * HID * 2);    // 12.8 MB

    const int TPB = 256;
    const int* esrc = ei;
    const int* edst = ei + E;
    const int waveBlocks = ((size_t)N * 64 + TPB - 1) / TPB;

    // CSR build — zero global atomics
    k_hist<<<C, 512, 0, stream>>>(edst, E, C, NB, histT);
    k_scan1<<<nScan, TPB, 0, stream>>>(histT, L, histT, blocksums);
    k_scan2<<<1, 512, 0, stream>>>(blocksums, nScan, blockoff);
    k_scan3f<<<(L + TPB - 1) / TPB, TPB, 0, stream>>>(histT, blockoff, L);
    k_scatterbin<<<C, 512, 0, stream>>>(esrc, edst, E, C, NB, histT, bucket);
    k_csrbuild<<<NB, TPB, 0, stream>>>(histT, C, NB, E, bucket, csr, rowptr, dis, N);

    // xs table (needs dis)
    k_xs<<<((N * XPAD) + TPB - 1) / TPB, TPB, 0, stream>>>(x, dis, xs, N);

    // layer 1: x-space gather + W1 + relu -> a (bf16)
    k_agg1x<<<waveBlocks, TPB, 0, stream>>>(rowptr, csr, xs, dis, W1, b1, a_bf, N);

    // dense a@W2 -> g2 (bf16)
    k_xw2b<<<2048, TPB, 0, stream>>>(a_bf, W2, dis, g2, N);

    // layer 2: packed-gather aggregation + head
    k_agg2_head<<<waveBlocks, TPB, 0, stream>>>(rowptr, csr, g2, dis, b2, Wl, bl, out, N);
}

// Round 19
// 198.377 us; speedup vs baseline: 21.5830x; 1.0150x over previous
//
#include <hip/hip_runtime.h>

// GCN 2-layer + head.
// R19: (a) gather full-group loops unrolled x4 (all ~4 groups of a typical
//      32-edge row issue their loads in one iteration); (b) k_xs folded into
//      k_csrbuild's epilogue (dis already on-block; saves a dispatch and a
//      re-read of dis). All-lane tail shfl (R18 correctness rule) retained.
// bucket word = (src<<7) | (dst&127), src < 2^17 fits 24 bits.

#define HID 64
#define INC 11
#define XPAD 16
#define BINSH 7
#define BINW 128
#define MAXNB 800      // >= ceil(100000/128)=782
#define ECHUNK 8192
#define SCAN_CHUNK 1024
#define STAGE_MAX 6144

typedef unsigned short bf16t;

__device__ __forceinline__ bf16t f2b(float f) {
    union { float ff; unsigned int i; } v;
    v.ff = f;
    unsigned int r = v.i + 0x7FFF + ((v.i >> 16) & 1);   // RNE
    return (bf16t)(r >> 16);
}
__device__ __forceinline__ float blo(unsigned int u) {
    union { float f; unsigned int i; } v; v.i = u << 16; return v.f;
}
__device__ __forceinline__ float bhi(unsigned int u) {
    union { float f; unsigned int i; } v; v.i = u & 0xFFFF0000u; return v.f;
}
__device__ __forceinline__ float rdlane(float v, int l) {
    union { float f; int i; } u; u.f = v;
    u.i = __builtin_amdgcn_readlane(u.i, l);
    return u.f;
}

// ---- per-chunk histogram of dst bins, stored transposed histT[b*C+c] ----
__global__ void k_hist(const int* __restrict__ dst, int E, int C, int NB,
                       int* __restrict__ histT) {
    __shared__ int h[MAXNB];
    int c = blockIdx.x, t = threadIdx.x;    // 512 threads
    for (int i = t; i < NB; i += 512) h[i] = 0;
    __syncthreads();
    int base = c * ECHUNK;
    int end = min(base + ECHUNK, E);
    int n4 = (end - base) >> 2;
    const int4* d4 = (const int4*)(dst + base);
    for (int i = t; i < n4; i += 512) {
        int4 d = d4[i];
        atomicAdd(&h[d.x >> BINSH], 1);
        atomicAdd(&h[d.y >> BINSH], 1);
        atomicAdd(&h[d.z >> BINSH], 1);
        atomicAdd(&h[d.w >> BINSH], 1);
    }
    __syncthreads();
    for (int b = t; b < NB; b += 512)
        histT[(size_t)b * C + c] = h[b];
}

// ---- generic 3-kernel exclusive scan (in-place safe), L <= 512*SCAN_CHUNK ----
__global__ void k_scan1(const int* __restrict__ in, int L,
                        int* __restrict__ part, int* __restrict__ blocksums) {
    __shared__ int lds[SCAN_CHUNK];
    __shared__ int tsum[256];
    int b = blockIdx.x, t = threadIdx.x;
    int base = b * SCAN_CHUNK;
    for (int i = t; i < SCAN_CHUNK; i += 256)
        lds[i] = (base + i < L) ? in[base + i] : 0;
    __syncthreads();
    int a0 = lds[t*4], a1 = lds[t*4+1], a2 = lds[t*4+2], a3 = lds[t*4+3];
    int ts = a0 + a1 + a2 + a3;
    tsum[t] = ts;
    __syncthreads();
    for (int off = 1; off < 256; off <<= 1) {
        int v = (t >= off) ? tsum[t - off] : 0;
        __syncthreads();
        tsum[t] += v;
        __syncthreads();
    }
    int excl = tsum[t] - ts;
    int i0 = base + t*4;
    if (i0     < L) part[i0]     = excl;
    if (i0 + 1 < L) part[i0 + 1] = excl + a0;
    if (i0 + 2 < L) part[i0 + 2] = excl + a0 + a1;
    if (i0 + 3 < L) part[i0 + 3] = excl + a0 + a1 + a2;
    if (t == 255) blocksums[b] = tsum[255];
}

__global__ void k_scan2(const int* __restrict__ blocksums, int nb, int* __restrict__ blockoff) {
    __shared__ int s[512];
    int t = threadIdx.x;    // 512 threads
    s[t] = (t < nb) ? blocksums[t] : 0;
    __syncthreads();
    int mine = s[t];
    for (int off = 1; off < 512; off <<= 1) {
        int v = (t >= off) ? s[t - off] : 0;
        __syncthreads();
        s[t] += v;
        __syncthreads();
    }
    blockoff[t] = s[t] - mine;   // exclusive
}

__global__ void k_scan3f(int* __restrict__ part, const int* __restrict__ blockoff, int L) {
    int i = blockIdx.x * blockDim.x + threadIdx.x;
    if (i < L) part[i] += blockoff[i / SCAN_CHUNK];
}

// ---- scatter edges into bin-grouped bucket; rank via LDS atomic, 8 chains ----
__global__ void k_scatterbin(const int* __restrict__ src, const int* __restrict__ dst,
                             int E, int C, int NB, const int* __restrict__ scanT,
                             int* __restrict__ bucket) {
    __shared__ int cur[MAXNB];
    int c = blockIdx.x, t = threadIdx.x;    // 512 threads
    for (int b = t; b < NB; b += 512) cur[b] = scanT[(size_t)b * C + c];
    __syncthreads();
    int base = c * ECHUNK;
    int end = min(base + ECHUNK, E);
    int n4 = (end - base) >> 2;
    const int4* d4 = (const int4*)(dst + base);
    const int4* s4 = (const int4*)(src + base);
    for (int i = t; i < n4; i += 1024) {
        int4 da = d4[i], sa = s4[i];
        bool hb = (i + 512) < n4;
        int4 db, sb;
        if (hb) { db = d4[i + 512]; sb = s4[i + 512]; }
        int r0 = atomicAdd(&cur[da.x >> BINSH], 1);
        int r1 = atomicAdd(&cur[da.y >> BINSH], 1);
        int r2 = atomicAdd(&cur[da.z >> BINSH], 1);
        int r3 = atomicAdd(&cur[da.w >> BINSH], 1);
        int r4 = 0, r5 = 0, r6 = 0, r7 = 0;
        if (hb) {
            r4 = atomicAdd(&cur[db.x >> BINSH], 1);
            r5 = atomicAdd(&cur[db.y >> BINSH], 1);
            r6 = atomicAdd(&cur[db.z >> BINSH], 1);
            r7 = atomicAdd(&cur[db.w >> BINSH], 1);
        }
        bucket[r0] = (sa.x << BINSH) | (da.x & (BINW - 1));
        bucket[r1] = (sa.y << BINSH) | (da.y & (BINW - 1));
        bucket[r2] = (sa.z << BINSH) | (da.z & (BINW - 1));
        bucket[r3] = (sa.w << BINSH) | (da.w & (BINW - 1));
        if (hb) {
            bucket[r4] = (sb.x << BINSH) | (db.x & (BINW - 1));
            bucket[r5] = (sb.y << BINSH) | (db.y & (BINW - 1));
            bucket[r6] = (sb.z << BINSH) | (db.z & (BINW - 1));
            bucket[r7] = (sb.w << BINSH) | (db.w & (BINW - 1));
        }
    }
}

// ---- per-bin CSR finalize + fused xs epilogue ----
__global__ void k_csrbuild(const int* __restrict__ scanT, int C, int NB, int E,
                           const int* __restrict__ bucket, int* __restrict__ csr,
                           int* __restrict__ rowptr, float* __restrict__ dis,
                           const float* __restrict__ x, bf16t* __restrict__ xs, int N) {
    __shared__ int cnt[BINW];
    __shared__ int ex[BINW];
    __shared__ int cur[BINW];
    __shared__ float disl[BINW];
    __shared__ int stage[STAGE_MAX];
    int b = blockIdx.x, t = threadIdx.x;
    int s = scanT[(size_t)b * C];
    int e = (b + 1 < NB) ? scanT[(size_t)(b + 1) * C] : E;
    int len = e - s;
    if (t < BINW) cnt[t] = 0;
    __syncthreads();
    for (int p = s + t; p < e; p += 256)
        atomicAdd(&cnt[bucket[p] & (BINW - 1)], 1);
    __syncthreads();
    if (t < BINW) ex[t] = cnt[t];
    __syncthreads();
    for (int off = 1; off < BINW; off <<= 1) {
        int v = (t < BINW && t >= off) ? ex[t - off] : 0;
        __syncthreads();
        if (t < BINW) ex[t] += v;
        __syncthreads();
    }
    if (t < BINW) {
        int excl = ex[t] - cnt[t];
        cur[t] = excl;
        int n = b * BINW + t;
        if (n <= N) rowptr[n] = s + excl;
        if (n < N) {
            float d = rsqrtf((float)(cnt[t] + 1));
            dis[n] = d;
            disl[t] = d;
        }
    }
    __syncthreads();   // disl + cur ready
    if (len <= STAGE_MAX) {
        for (int p = s + t; p < e; p += 256) {
            int w = bucket[p];
            int r = atomicAdd(&cur[w & (BINW - 1)], 1);
            stage[r] = w >> BINSH;
        }
        __syncthreads();
        for (int i = t; i < len; i += 256) csr[s + i] = stage[i];
    } else {
        for (int p = s + t; p < e; p += 256) {
            int w = bucket[p];
            int r = atomicAdd(&cur[w & (BINW - 1)], 1);
            csr[s + r] = w >> BINSH;
        }
    }
    // fused xs epilogue: xs[n][f] = bf16(dis[n]*x[n][f]) for this bin's rows
    int nrows = min(BINW, N - b * BINW);
    for (int i = t; i < nrows * XPAD; i += 256) {
        int r = i >> 4, f = i & 15;
        int n = b * BINW + r;
        float v = (f < INC) ? disl[r] * x[(size_t)n * INC + f] : 0.f;
        xs[(size_t)n * XPAD + f] = f2b(v);
    }
}

// ---- layer-1: packed x-space gather + W1 (readlane) + relu -> a[N][64] bf16 ----
// gather: lane = (slot = l>>3 of 8 edges, pair = l&7 -> features 2p, 2p+1).
__global__ void k_agg1x(const int* __restrict__ rowptr, const int* __restrict__ csr,
                        const bf16t* __restrict__ xs, const float* __restrict__ dis,
                        const float* __restrict__ W1, const float* __restrict__ b1,
                        bf16t* __restrict__ a_out, int N) {
    __shared__ float W1s[INC * HID];   // 2.75 KB (only LDS in kernel)
    int t = threadIdx.x;
    for (int i = t; i < INC * HID; i += 256) W1s[i] = W1[i];
    __syncthreads();
    int lane = t & 63;
    int row = (blockIdx.x * blockDim.x + t) >> 6;
    if (row >= N) return;
    int pr = lane & 7;       // feature pair: features 2*pr, 2*pr+1
    int slot = lane >> 3;    // 8 edge slots
    int p0 = rowptr[row], p1 = rowptr[row + 1];
    float a0 = 0.f, a1 = 0.f;
    for (int p = p0; p < p1; p += 64) {
        int idx = (p + lane < p1) ? csr[p + lane] : 0;
        int cnt = min(64, p1 - p);
        int nfull = cnt >> 3;            // wave-uniform -> no divergence
        int j = 0;
        for (; j + 4 <= nfull; j += 4) { // 4 independent loads in flight
            int sA = __shfl(idx, j * 8 + slot);
            int sB = __shfl(idx, j * 8 + 8 + slot);
            int sC = __shfl(idx, j * 8 + 16 + slot);
            int sD = __shfl(idx, j * 8 + 24 + slot);
            unsigned int uA = *(const unsigned int*)(xs + (size_t)sA * XPAD + pr * 2);
            unsigned int uB = *(const unsigned int*)(xs + (size_t)sB * XPAD + pr * 2);
            unsigned int uC = *(const unsigned int*)(xs + (size_t)sC * XPAD + pr * 2);
            unsigned int uD = *(const unsigned int*)(xs + (size_t)sD * XPAD + pr * 2);
            a0 += blo(uA); a1 += bhi(uA);
            a0 += blo(uB); a1 += bhi(uB);
            a0 += blo(uC); a1 += bhi(uC);
            a0 += blo(uD); a1 += bhi(uD);
        }
        for (; j + 2 <= nfull; j += 2) {
            int sA = __shfl(idx, j * 8 + slot);
            int sB = __shfl(idx, j * 8 + 8 + slot);
            unsigned int uA = *(const unsigned int*)(xs + (size_t)sA * XPAD + pr * 2);
            unsigned int uB = *(const unsigned int*)(xs + (size_t)sB * XPAD + pr * 2);
            a0 += blo(uA); a1 += bhi(uA);
            a0 += blo(uB); a1 += bhi(uB);
        }
        for (; j < nfull; ++j) {
            int sA = __shfl(idx, j * 8 + slot);
            unsigned int uA = *(const unsigned int*)(xs + (size_t)sA * XPAD + pr * 2);
            a0 += blo(uA); a1 += bhi(uA);
        }
        // tail: shfl by ALL lanes (bpermute needs active source lanes)
        int q = nfull * 8 + slot;
        int sA = __shfl(idx, q & 63);
        if (q < cnt) {
            unsigned int uA = *(const unsigned int*)(xs + (size_t)sA * XPAD + pr * 2);
            a0 += blo(uA); a1 += bhi(uA);
        }
    }
    // reduce across the 8 edge slots (lane bits 3,4,5)
    #pragma unroll
    for (int mask = 8; mask <= 32; mask <<= 1) {
        a0 += __shfl_xor(a0, mask);
        a1 += __shfl_xor(a1, mask);
    }
    // self-loop AFTER reduce (each lane adds its own pair exactly once)
    {
        unsigned int us = *(const unsigned int*)(xs + (size_t)row * XPAD + pr * 2);
        a0 += blo(us);
        a1 += bhi(us);
    }
    float d = dis[row];
    float pre = 0.f;
    #pragma unroll
    for (int k = 0; k < INC; ++k) {
        float xv = (k & 1) ? rdlane(a1, k >> 1) : rdlane(a0, k >> 1);
        pre += xv * W1s[k * HID + lane];
    }
    float a = d * pre + b1[lane];
    a = a > 0.f ? a : 0.f;
    a_out[(size_t)row * HID + lane] = f2b(a);
}

// ---- dense GEMM: g2[row][c] = bf16(dis[row] * (a[row] @ W2)[c]) ----
__global__ void k_xw2b(const bf16t* __restrict__ a, const float* __restrict__ W2,
                       const float* __restrict__ dis, bf16t* __restrict__ g2, int N) {
    __shared__ float Ws[HID * HID];   // 16 KB
    int t = threadIdx.x;
    for (int i = t; i < HID * HID; i += 256) Ws[i] = W2[i];
    __syncthreads();
    int c = t & 63;
    for (int row = blockIdx.x * 4 + (t >> 6); row < N; row += gridDim.x * 4) {
        const uint4* r4 = (const uint4*)(a + (size_t)row * HID);
        float acc = 0.f;
        #pragma unroll
        for (int q = 0; q < 8; ++q) {
            uint4 u = r4[q];
            int k = q * 8;
            acc += blo(u.x) * Ws[(k    ) * HID + c];
            acc += bhi(u.x) * Ws[(k + 1) * HID + c];
            acc += blo(u.y) * Ws[(k + 2) * HID + c];
            acc += bhi(u.y) * Ws[(k + 3) * HID + c];
            acc += blo(u.z) * Ws[(k + 4) * HID + c];
            acc += bhi(u.z) * Ws[(k + 5) * HID + c];
            acc += blo(u.w) * Ws[(k + 6) * HID + c];
            acc += bhi(u.w) * Ws[(k + 7) * HID + c];
        }
        g2[(size_t)row * HID + c] = f2b(dis[row] * acc);
    }
}

// ---- layer-2 aggregation, packed uint4 gather, full groups unrolled x4,
//      all-lane tail shfl; fused head. wave per row. ----
__global__ void k_agg2_head(const int* __restrict__ rowptr, const int* __restrict__ csr,
                            const bf16t* __restrict__ g, const float* __restrict__ dis,
                            const float* __restrict__ b2, const float* __restrict__ Wl,
                            const float* __restrict__ bl, float* __restrict__ out, int N) {
    int lane = threadIdx.x & 63;
    int row = (blockIdx.x * blockDim.x + threadIdx.x) >> 6;
    if (row >= N) return;
    int h = lane & 7;        // feature octet: features h*8 .. h*8+7
    int slot = lane >> 3;    // 8 edge slots
    int s = rowptr[row], e = rowptr[row + 1];
    float a0 = 0.f, a1 = 0.f, a2 = 0.f, a3 = 0.f, a4 = 0.f, a5 = 0.f, a6 = 0.f, a7 = 0.f;
    for (int p = s; p < e; p += 64) {
        int idx = (p + lane < e) ? csr[p + lane] : 0;
        int cnt = min(64, e - p);
        int nfull = cnt >> 3;              // wave-uniform
        int j = 0;
        for (; j + 4 <= nfull; j += 4) {   // 4 independent loads in flight
            int sA = __shfl(idx, j * 8 + slot);
            int sB = __shfl(idx, j * 8 + 8 + slot);
            int sC = __shfl(idx, j * 8 + 16 + slot);
            int sD = __shfl(idx, j * 8 + 24 + slot);
            const uint4 vA = *(const uint4*)(g + (size_t)sA * HID + h * 8);
            const uint4 vB = *(const uint4*)(g + (size_t)sB * HID + h * 8);
            const uint4 vC = *(const uint4*)(g + (size_t)sC * HID + h * 8);
            const uint4 vD = *(const uint4*)(g + (size_t)sD * HID + h * 8);
            a0 += blo(vA.x); a1 += bhi(vA.x); a2 += blo(vA.y); a3 += bhi(vA.y);
            a4 += blo(vA.z); a5 += bhi(vA.z); a6 += blo(vA.w); a7 += bhi(vA.w);
            a0 += blo(vB.x); a1 += bhi(vB.x); a2 += blo(vB.y); a3 += bhi(vB.y);
            a4 += blo(vB.z); a5 += bhi(vB.z); a6 += blo(vB.w); a7 += bhi(vB.w);
            a0 += blo(vC.x); a1 += bhi(vC.x); a2 += blo(vC.y); a3 += bhi(vC.y);
            a4 += blo(vC.z); a5 += bhi(vC.z); a6 += blo(vC.w); a7 += bhi(vC.w);
            a0 += blo(vD.x); a1 += bhi(vD.x); a2 += blo(vD.y); a3 += bhi(vD.y);
            a4 += blo(vD.z); a5 += bhi(vD.z); a6 += blo(vD.w); a7 += bhi(vD.w);
        }
        for (; j + 2 <= nfull; j += 2) {
            int sA = __shfl(idx, j * 8 + slot);
            int sB = __shfl(idx, j * 8 + 8 + slot);
            const uint4 vA = *(const uint4*)(g + (size_t)sA * HID + h * 8);
            const uint4 vB = *(const uint4*)(g + (size_t)sB * HID + h * 8);
            a0 += blo(vA.x); a1 += bhi(vA.x); a2 += blo(vA.y); a3 += bhi(vA.y);
            a4 += blo(vA.z); a5 += bhi(vA.z); a6 += blo(vA.w); a7 += bhi(vA.w);
            a0 += blo(vB.x); a1 += bhi(vB.x); a2 += blo(vB.y); a3 += bhi(vB.y);
            a4 += blo(vB.z); a5 += bhi(vB.z); a6 += blo(vB.w); a7 += bhi(vB.w);
        }
        for (; j < nfull; ++j) {
            int sA = __shfl(idx, j * 8 + slot);
            const uint4 vA = *(const uint4*)(g + (size_t)sA * HID + h * 8);
            a0 += blo(vA.x); a1 += bhi(vA.x); a2 += blo(vA.y); a3 += bhi(vA.y);
            a4 += blo(vA.z); a5 += bhi(vA.z); a6 += blo(vA.w); a7 += bhi(vA.w);
        }
        // tail: shfl by ALL lanes, divergent load+add only
        int q = nfull * 8 + slot;
        int sA = __shfl(idx, q & 63);
        if (q < cnt) {
            const uint4 vA = *(const uint4*)(g + (size_t)sA * HID + h * 8);
            a0 += blo(vA.x); a1 += bhi(vA.x); a2 += blo(vA.y); a3 += bhi(vA.y);
            a4 += blo(vA.z); a5 += bhi(vA.z); a6 += blo(vA.w); a7 += bhi(vA.w);
        }
    }
    // reduce across the 8 edge slots (lane bits 3,4,5)
    #pragma unroll
    for (int mask = 8; mask <= 32; mask <<= 1) {
        a0 += __shfl_xor(a0, mask); a1 += __shfl_xor(a1, mask);
        a2 += __shfl_xor(a2, mask); a3 += __shfl_xor(a3, mask);
        a4 += __shfl_xor(a4, mask); a5 += __shfl_xor(a5, mask);
        a6 += __shfl_xor(a6, mask); a7 += __shfl_xor(a7, mask);
    }
    // self-loop AFTER reduce (each lane adds its own octet exactly once)
    {
        const uint4 gv = *(const uint4*)(g + (size_t)row * HID + h * 8);
        a0 += blo(gv.x); a1 += bhi(gv.x);
        a2 += blo(gv.y); a3 += bhi(gv.y);
        a4 += blo(gv.z); a5 += bhi(gv.z);
        a6 += blo(gv.w); a7 += bhi(gv.w);
    }
    // head: relu(d*acc + b2) . Wl over this lane's 8 features
    float d = dis[row];
    float4 blo4 = *(const float4*)(b2 + h * 8);
    float4 bhi4 = *(const float4*)(b2 + h * 8 + 4);
    float4 wlo4 = *(const float4*)(Wl + h * 8);
    float4 whi4 = *(const float4*)(Wl + h * 8 + 4);
    float part = 0.f;
    float v;
    v = d * a0 + blo4.x; v = v > 0.f ? v : 0.f; part += v * wlo4.x;
    v = d * a1 + blo4.y; v = v > 0.f ? v : 0.f; part += v * wlo4.y;
    v = d * a2 + blo4.z; v = v > 0.f ? v : 0.f; part += v * wlo4.z;
    v = d * a3 + blo4.w; v = v > 0.f ? v : 0.f; part += v * wlo4.w;
    v = d * a4 + bhi4.x; v = v > 0.f ? v : 0.f; part += v * whi4.x;
    v = d * a5 + bhi4.y; v = v > 0.f ? v : 0.f; part += v * whi4.y;
    v = d * a6 + bhi4.z; v = v > 0.f ? v : 0.f; part += v * whi4.z;
    v = d * a7 + bhi4.w; v = v > 0.f ? v : 0.f; part += v * whi4.w;
    // reduce across the 8 octets (lane bits 0,1,2)
    part += __shfl_xor(part, 1);
    part += __shfl_xor(part, 2);
    part += __shfl_xor(part, 4);
    if (lane == 0) out[row] = part + bl[0];
}

extern "C" void kernel_launch(void* const* d_in, const int* in_sizes, int n_in,
                              void* d_out, int out_size, void* d_ws, size_t ws_size,
                              hipStream_t stream) {
    const float* x  = (const float*)d_in[0];
    const int*   ei = (const int*)d_in[1];
    const float* W1 = (const float*)d_in[2];
    const float* b1 = (const float*)d_in[3];
    const float* W2 = (const float*)d_in[4];
    const float* b2 = (const float*)d_in[5];
    const float* Wl = (const float*)d_in[6];
    const float* bl = (const float*)d_in[7];
    float* out = (float*)d_out;

    const int N = in_sizes[0] / INC;    // 100000
    const int E = in_sizes[1] / 2;      // 3200000
    const int NB = (N + BINW - 1) / BINW;        // 782
    const int C  = (E + ECHUNK - 1) / ECHUNK;    // 391
    const int L  = NB * C;                        // 305762
    const int nScan = (L + SCAN_CHUNK - 1) / SCAN_CHUNK;  // 299 (<=512)

    char* ws = (char*)d_ws;
    size_t off = 0;
    auto alloc = [&](size_t bytes) { void* p = ws + off; off += (bytes + 255) / 256 * 256; return p; };
    int*   histT    = (int*)alloc((size_t)L * 4);     // scanned in place
    int*   blocksums= (int*)alloc(512 * 4);
    int*   blockoff = (int*)alloc(512 * 4);
    int*   rowptr   = (int*)alloc((size_t)(N + 1) * 4);
    float* dis      = (float*)alloc((size_t)N * 4);
    int*   csr      = (int*)alloc((size_t)E * 4);
    int*   bucket   = (int*)alloc((size_t)E * 4);
    bf16t* xs       = (bf16t*)alloc((size_t)N * XPAD * 2);   // 3.2 MB
    bf16t* a_bf     = (bf16t*)alloc((size_t)N * HID * 2);    // 12.8 MB
    bf16t* g2       = (bf16t*)alloc((size_t)N * HID * 2);    // 12.8 MB

    const int TPB = 256;
    const int* esrc = ei;
    const int* edst = ei + E;
    const int waveBlocks = ((size_t)N * 64 + TPB - 1) / TPB;

    // CSR build — zero global atomics; csrbuild also emits dis + xs
    k_hist<<<C, 512, 0, stream>>>(edst, E, C, NB, histT);
    k_scan1<<<nScan, TPB, 0, stream>>>(histT, L, histT, blocksums);
    k_scan2<<<1, 512, 0, stream>>>(blocksums, nScan, blockoff);
    k_scan3f<<<(L + TPB - 1) / TPB, TPB, 0, stream>>>(histT, blockoff, L);
    k_scatterbin<<<C, 512, 0, stream>>>(esrc, edst, E, C, NB, histT, bucket);
    k_csrbuild<<<NB, TPB, 0, stream>>>(histT, C, NB, E, bucket, csr, rowptr, dis, x, xs, N);

    // layer 1: x-space gather + W1 + relu -> a (bf16)
    k_agg1x<<<waveBlocks, TPB, 0, stream>>>(rowptr, csr, xs, dis, W1, b1, a_bf, N);

    // dense a@W2 -> g2 (bf16)
    k_xw2b<<<2048, TPB, 0, stream>>>(a_bf, W2, dis, g2, N);

    // layer 2: packed-gather aggregation + head
    k_agg2_head<<<waveBlocks, TPB, 0, stream>>>(rowptr, csr, g2, dis, b2, Wl, bl, out, N);
}

// Round 20
// 196.425 us; speedup vs baseline: 21.7975x; 1.0099x over previous
//
#include <hip/hip_runtime.h>

// GCN 2-layer + head.
// R20: 256-node bins (BINSH 8). Doubles the per-(chunk,bin) write-run length
//      in scatterbin (~42 B -> ~84 B) to cut scattered-store line waste —
//      scatterbin was at its store-fill limit. csrbuild: BINW=256 scan,
//      STAGE_MAX 9216 (40 KB LDS). Aggregation kernels unchanged from R19.
// bucket word = (src<<8) | (dst&255), src < 2^17 fits 25 bits.

#define HID 64
#define INC 11
#define XPAD 16
#define BINSH 8
#define BINW 256
#define MAXNB 400      // >= ceil(100000/256)=391
#define ECHUNK 8192
#define SCAN_CHUNK 1024
#define STAGE_MAX 9216 // bin length ~8192 +- 5 sigma (~460)

typedef unsigned short bf16t;

__device__ __forceinline__ bf16t f2b(float f) {
    union { float ff; unsigned int i; } v;
    v.ff = f;
    unsigned int r = v.i + 0x7FFF + ((v.i >> 16) & 1);   // RNE
    return (bf16t)(r >> 16);
}
__device__ __forceinline__ float blo(unsigned int u) {
    union { float f; unsigned int i; } v; v.i = u << 16; return v.f;
}
__device__ __forceinline__ float bhi(unsigned int u) {
    union { float f; unsigned int i; } v; v.i = u & 0xFFFF0000u; return v.f;
}
__device__ __forceinline__ float rdlane(float v, int l) {
    union { float f; int i; } u; u.f = v;
    u.i = __builtin_amdgcn_readlane(u.i, l);
    return u.f;
}

// ---- per-chunk histogram of dst bins, stored transposed histT[b*C+c] ----
__global__ void k_hist(const int* __restrict__ dst, int E, int C, int NB,
                       int* __restrict__ histT) {
    __shared__ int h[MAXNB];
    int c = blockIdx.x, t = threadIdx.x;    // 512 threads
    for (int i = t; i < NB; i += 512) h[i] = 0;
    __syncthreads();
    int base = c * ECHUNK;
    int end = min(base + ECHUNK, E);
    int n4 = (end - base) >> 2;
    const int4* d4 = (const int4*)(dst + base);
    for (int i = t; i < n4; i += 512) {
        int4 d = d4[i];
        atomicAdd(&h[d.x >> BINSH], 1);
        atomicAdd(&h[d.y >> BINSH], 1);
        atomicAdd(&h[d.z >> BINSH], 1);
        atomicAdd(&h[d.w >> BINSH], 1);
    }
    __syncthreads();
    for (int b = t; b < NB; b += 512)
        histT[(size_t)b * C + c] = h[b];
}

// ---- generic 3-kernel exclusive scan (in-place safe), L <= 512*SCAN_CHUNK ----
__global__ void k_scan1(const int* __restrict__ in, int L,
                        int* __restrict__ part, int* __restrict__ blocksums) {
    __shared__ int lds[SCAN_CHUNK];
    __shared__ int tsum[256];
    int b = blockIdx.x, t = threadIdx.x;
    int base = b * SCAN_CHUNK;
    for (int i = t; i < SCAN_CHUNK; i += 256)
        lds[i] = (base + i < L) ? in[base + i] : 0;
    __syncthreads();
    int a0 = lds[t*4], a1 = lds[t*4+1], a2 = lds[t*4+2], a3 = lds[t*4+3];
    int ts = a0 + a1 + a2 + a3;
    tsum[t] = ts;
    __syncthreads();
    for (int off = 1; off < 256; off <<= 1) {
        int v = (t >= off) ? tsum[t - off] : 0;
        __syncthreads();
        tsum[t] += v;
        __syncthreads();
    }
    int excl = tsum[t] - ts;
    int i0 = base + t*4;
    if (i0     < L) part[i0]     = excl;
    if (i0 + 1 < L) part[i0 + 1] = excl + a0;
    if (i0 + 2 < L) part[i0 + 2] = excl + a0 + a1;
    if (i0 + 3 < L) part[i0 + 3] = excl + a0 + a1 + a2;
    if (t == 255) blocksums[b] = tsum[255];
}

__global__ void k_scan2(const int* __restrict__ blocksums, int nb, int* __restrict__ blockoff) {
    __shared__ int s[512];
    int t = threadIdx.x;    // 512 threads
    s[t] = (t < nb) ? blocksums[t] : 0;
    __syncthreads();
    int mine = s[t];
    for (int off = 1; off < 512; off <<= 1) {
        int v = (t >= off) ? s[t - off] : 0;
        __syncthreads();
        s[t] += v;
        __syncthreads();
    }
    blockoff[t] = s[t] - mine;   // exclusive
}

__global__ void k_scan3f(int* __restrict__ part, const int* __restrict__ blockoff, int L) {
    int i = blockIdx.x * blockDim.x + threadIdx.x;
    if (i < L) part[i] += blockoff[i / SCAN_CHUNK];
}

// ---- scatter edges into bin-grouped bucket; rank via LDS atomic, 8 chains ----
__global__ void k_scatterbin(const int* __restrict__ src, const int* __restrict__ dst,
                             int E, int C, int NB, const int* __restrict__ scanT,
                             int* __restrict__ bucket) {
    __shared__ int cur[MAXNB];
    int c = blockIdx.x, t = threadIdx.x;    // 512 threads
    for (int b = t; b < NB; b += 512) cur[b] = scanT[(size_t)b * C + c];
    __syncthreads();
    int base = c * ECHUNK;
    int end = min(base + ECHUNK, E);
    int n4 = (end - base) >> 2;
    const int4* d4 = (const int4*)(dst + base);
    const int4* s4 = (const int4*)(src + base);
    for (int i = t; i < n4; i += 1024) {
        int4 da = d4[i], sa = s4[i];
        bool hb = (i + 512) < n4;
        int4 db, sb;
        if (hb) { db = d4[i + 512]; sb = s4[i + 512]; }
        int r0 = atomicAdd(&cur[da.x >> BINSH], 1);
        int r1 = atomicAdd(&cur[da.y >> BINSH], 1);
        int r2 = atomicAdd(&cur[da.z >> BINSH], 1);
        int r3 = atomicAdd(&cur[da.w >> BINSH], 1);
        int r4 = 0, r5 = 0, r6 = 0, r7 = 0;
        if (hb) {
            r4 = atomicAdd(&cur[db.x >> BINSH], 1);
            r5 = atomicAdd(&cur[db.y >> BINSH], 1);
            r6 = atomicAdd(&cur[db.z >> BINSH], 1);
            r7 = atomicAdd(&cur[db.w >> BINSH], 1);
        }
        bucket[r0] = (sa.x << BINSH) | (da.x & (BINW - 1));
        bucket[r1] = (sa.y << BINSH) | (da.y & (BINW - 1));
        bucket[r2] = (sa.z << BINSH) | (da.z & (BINW - 1));
        bucket[r3] = (sa.w << BINSH) | (da.w & (BINW - 1));
        if (hb) {
            bucket[r4] = (sb.x << BINSH) | (db.x & (BINW - 1));
            bucket[r5] = (sb.y << BINSH) | (db.y & (BINW - 1));
            bucket[r6] = (sb.z << BINSH) | (db.z & (BINW - 1));
            bucket[r7] = (sb.w << BINSH) | (db.w & (BINW - 1));
        }
    }
}

// ---- per-bin CSR finalize + fused xs epilogue (BINW=256) ----
__global__ void k_csrbuild(const int* __restrict__ scanT, int C, int NB, int E,
                           const int* __restrict__ bucket, int* __restrict__ csr,
                           int* __restrict__ rowptr, float* __restrict__ dis,
                           const float* __restrict__ x, bf16t* __restrict__ xs, int N) {
    __shared__ int cnt[BINW];
    __shared__ int ex[BINW];
    __shared__ int cur[BINW];
    __shared__ float disl[BINW];
    __shared__ int stage[STAGE_MAX];   // 36 KB
    int b = blockIdx.x, t = threadIdx.x;   // 256 threads
    int s = scanT[(size_t)b * C];
    int e = (b + 1 < NB) ? scanT[(size_t)(b + 1) * C] : E;
    int len = e - s;
    cnt[t] = 0;
    __syncthreads();
    for (int p = s + t; p < e; p += 256)
        atomicAdd(&cnt[bucket[p] & (BINW - 1)], 1);
    __syncthreads();
    ex[t] = cnt[t];
    __syncthreads();
    for (int off = 1; off < BINW; off <<= 1) {
        int v = (t >= off) ? ex[t - off] : 0;
        __syncthreads();
        ex[t] += v;
        __syncthreads();
    }
    {
        int excl = ex[t] - cnt[t];
        cur[t] = excl;
        int n = b * BINW + t;
        if (n <= N) rowptr[n] = s + excl;
        if (n < N) {
            float d = rsqrtf((float)(cnt[t] + 1));
            dis[n] = d;
            disl[t] = d;
        }
    }
    // last block also writes rowptr[N] if not covered (N = 100000, NB*BINW >= N)
    if (b == NB - 1 && t == 0) rowptr[N] = E;
    __syncthreads();   // disl + cur ready
    if (len <= STAGE_MAX) {
        for (int p = s + t; p < e; p += 256) {
            int w = bucket[p];
            int r = atomicAdd(&cur[w & (BINW - 1)], 1);
            stage[r] = w >> BINSH;
        }
        __syncthreads();
        for (int i = t; i < len; i += 256) csr[s + i] = stage[i];
    } else {
        for (int p = s + t; p < e; p += 256) {
            int w = bucket[p];
            int r = atomicAdd(&cur[w & (BINW - 1)], 1);
            csr[s + r] = w >> BINSH;
        }
    }
    // fused xs epilogue: xs[n][f] = bf16(dis[n]*x[n][f]) for this bin's rows
    int nrows = min(BINW, N - b * BINW);
    for (int i = t; i < nrows * XPAD; i += 256) {
        int r = i >> 4, f = i & 15;
        int n = b * BINW + r;
        float v = (f < INC) ? disl[r] * x[(size_t)n * INC + f] : 0.f;
        xs[(size_t)n * XPAD + f] = f2b(v);
    }
}

// ---- layer-1: packed x-space gather + W1 (readlane) + relu -> a[N][64] bf16 ----
__global__ void k_agg1x(const int* __restrict__ rowptr, const int* __restrict__ csr,
                        const bf16t* __restrict__ xs, const float* __restrict__ dis,
                        const float* __restrict__ W1, const float* __restrict__ b1,
                        bf16t* __restrict__ a_out, int N) {
    __shared__ float W1s[INC * HID];   // 2.75 KB (only LDS in kernel)
    int t = threadIdx.x;
    for (int i = t; i < INC * HID; i += 256) W1s[i] = W1[i];
    __syncthreads();
    int lane = t & 63;
    int row = (blockIdx.x * blockDim.x + t) >> 6;
    if (row >= N) return;
    int pr = lane & 7;       // feature pair: features 2*pr, 2*pr+1
    int slot = lane >> 3;    // 8 edge slots
    int p0 = rowptr[row], p1 = rowptr[row + 1];
    float a0 = 0.f, a1 = 0.f;
    for (int p = p0; p < p1; p += 64) {
        int idx = (p + lane < p1) ? csr[p + lane] : 0;
        int cnt = min(64, p1 - p);
        int nfull = cnt >> 3;            // wave-uniform -> no divergence
        int j = 0;
        for (; j + 4 <= nfull; j += 4) { // 4 independent loads in flight
            int sA = __shfl(idx, j * 8 + slot);
            int sB = __shfl(idx, j * 8 + 8 + slot);
            int sC = __shfl(idx, j * 8 + 16 + slot);
            int sD = __shfl(idx, j * 8 + 24 + slot);
            unsigned int uA = *(const unsigned int*)(xs + (size_t)sA * XPAD + pr * 2);
            unsigned int uB = *(const unsigned int*)(xs + (size_t)sB * XPAD + pr * 2);
            unsigned int uC = *(const unsigned int*)(xs + (size_t)sC * XPAD + pr * 2);
            unsigned int uD = *(const unsigned int*)(xs + (size_t)sD * XPAD + pr * 2);
            a0 += blo(uA); a1 += bhi(uA);
            a0 += blo(uB); a1 += bhi(uB);
            a0 += blo(uC); a1 += bhi(uC);
            a0 += blo(uD); a1 += bhi(uD);
        }
        for (; j + 2 <= nfull; j += 2) {
            int sA = __shfl(idx, j * 8 + slot);
            int sB = __shfl(idx, j * 8 + 8 + slot);
            unsigned int uA = *(const unsigned int*)(xs + (size_t)sA * XPAD + pr * 2);
            unsigned int uB = *(const unsigned int*)(xs + (size_t)sB * XPAD + pr * 2);
            a0 += blo(uA); a1 += bhi(uA);
            a0 += blo(uB); a1 += bhi(uB);
        }
        for (; j < nfull; ++j) {
            int sA = __shfl(idx, j * 8 + slot);
            unsigned int uA = *(const unsigned int*)(xs + (size_t)sA * XPAD + pr * 2);
            a0 += blo(uA); a1 += bhi(uA);
        }
        // tail: shfl by ALL lanes (bpermute needs active source lanes)
        int q = nfull * 8 + slot;
        int sA = __shfl(idx, q & 63);
        if (q < cnt) {
            unsigned int uA = *(const unsigned int*)(xs + (size_t)sA * XPAD + pr * 2);
            a0 += blo(uA); a1 += bhi(uA);
        }
    }
    #pragma unroll
    for (int mask = 8; mask <= 32; mask <<= 1) {
        a0 += __shfl_xor(a0, mask);
        a1 += __shfl_xor(a1, mask);
    }
    // self-loop AFTER reduce
    {
        unsigned int us = *(const unsigned int*)(xs + (size_t)row * XPAD + pr * 2);
        a0 += blo(us);
        a1 += bhi(us);
    }
    float d = dis[row];
    float pre = 0.f;
    #pragma unroll
    for (int k = 0; k < INC; ++k) {
        float xv = (k & 1) ? rdlane(a1, k >> 1) : rdlane(a0, k >> 1);
        pre += xv * W1s[k * HID + lane];
    }
    float a = d * pre + b1[lane];
    a = a > 0.f ? a : 0.f;
    a_out[(size_t)row * HID + lane] = f2b(a);
}

// ---- dense GEMM: g2[row][c] = bf16(dis[row] * (a[row] @ W2)[c]) ----
__global__ void k_xw2b(const bf16t* __restrict__ a, const float* __restrict__ W2,
                       const float* __restrict__ dis, bf16t* __restrict__ g2, int N) {
    __shared__ float Ws[HID * HID];   // 16 KB
    int t = threadIdx.x;
    for (int i = t; i < HID * HID; i += 256) Ws[i] = W2[i];
    __syncthreads();
    int c = t & 63;
    for (int row = blockIdx.x * 4 + (t >> 6); row < N; row += gridDim.x * 4) {
        const uint4* r4 = (const uint4*)(a + (size_t)row * HID);
        float acc = 0.f;
        #pragma unroll
        for (int q = 0; q < 8; ++q) {
            uint4 u = r4[q];
            int k = q * 8;
            acc += blo(u.x) * Ws[(k    ) * HID + c];
            acc += bhi(u.x) * Ws[(k + 1) * HID + c];
            acc += blo(u.y) * Ws[(k + 2) * HID + c];
            acc += bhi(u.y) * Ws[(k + 3) * HID + c];
            acc += blo(u.z) * Ws[(k + 4) * HID + c];
            acc += bhi(u.z) * Ws[(k + 5) * HID + c];
            acc += blo(u.w) * Ws[(k + 6) * HID + c];
            acc += bhi(u.w) * Ws[(k + 7) * HID + c];
        }
        g2[(size_t)row * HID + c] = f2b(dis[row] * acc);
    }
}

// ---- layer-2 aggregation, packed uint4 gather, x4 unroll, fused head ----
__global__ void k_agg2_head(const int* __restrict__ rowptr, const int* __restrict__ csr,
                            const bf16t* __restrict__ g, const float* __restrict__ dis,
                            const float* __restrict__ b2, const float* __restrict__ Wl,
                            const float* __restrict__ bl, float* __restrict__ out, int N) {
    int lane = threadIdx.x & 63;
    int row = (blockIdx.x * blockDim.x + threadIdx.x) >> 6;
    if (row >= N) return;
    int h = lane & 7;        // feature octet
    int slot = lane >> 3;    // 8 edge slots
    int s = rowptr[row], e = rowptr[row + 1];
    float a0 = 0.f, a1 = 0.f, a2 = 0.f, a3 = 0.f, a4 = 0.f, a5 = 0.f, a6 = 0.f, a7 = 0.f;
    for (int p = s; p < e; p += 64) {
        int idx = (p + lane < e) ? csr[p + lane] : 0;
        int cnt = min(64, e - p);
        int nfull = cnt >> 3;              // wave-uniform
        int j = 0;
        for (; j + 4 <= nfull; j += 4) {   // 4 independent loads in flight
            int sA = __shfl(idx, j * 8 + slot);
            int sB = __shfl(idx, j * 8 + 8 + slot);
            int sC = __shfl(idx, j * 8 + 16 + slot);
            int sD = __shfl(idx, j * 8 + 24 + slot);
            const uint4 vA = *(const uint4*)(g + (size_t)sA * HID + h * 8);
            const uint4 vB = *(const uint4*)(g + (size_t)sB * HID + h * 8);
            const uint4 vC = *(const uint4*)(g + (size_t)sC * HID + h * 8);
            const uint4 vD = *(const uint4*)(g + (size_t)sD * HID + h * 8);
            a0 += blo(vA.x); a1 += bhi(vA.x); a2 += blo(vA.y); a3 += bhi(vA.y);
            a4 += blo(vA.z); a5 += bhi(vA.z); a6 += blo(vA.w); a7 += bhi(vA.w);
            a0 += blo(vB.x); a1 += bhi(vB.x); a2 += blo(vB.y); a3 += bhi(vB.y);
            a4 += blo(vB.z); a5 += bhi(vB.z); a6 += blo(vB.w); a7 += bhi(vB.w);
            a0 += blo(vC.x); a1 += bhi(vC.x); a2 += blo(vC.y); a3 += bhi(vC.y);
            a4 += blo(vC.z); a5 += bhi(vC.z); a6 += blo(vC.w); a7 += bhi(vC.w);
            a0 += blo(vD.x); a1 += bhi(vD.x); a2 += blo(vD.y); a3 += bhi(vD.y);
            a4 += blo(vD.z); a5 += bhi(vD.z); a6 += blo(vD.w); a7 += bhi(vD.w);
        }
        for (; j + 2 <= nfull; j += 2) {
            int sA = __shfl(idx, j * 8 + slot);
            int sB = __shfl(idx, j * 8 + 8 + slot);
            const uint4 vA = *(const uint4*)(g + (size_t)sA * HID + h * 8);
            const uint4 vB = *(const uint4*)(g + (size_t)sB * HID + h * 8);
            a0 += blo(vA.x); a1 += bhi(vA.x); a2 += blo(vA.y); a3 += bhi(vA.y);
            a4 += blo(vA.z); a5 += bhi(vA.z); a6 += blo(vA.w); a7 += bhi(vA.w);
            a0 += blo(vB.x); a1 += bhi(vB.x); a2 += blo(vB.y); a3 += bhi(vB.y);
            a4 += blo(vB.z); a5 += bhi(vB.z); a6 += blo(vB.w); a7 += bhi(vB.w);
        }
        for (; j < nfull; ++j) {
            int sA = __shfl(idx, j * 8 + slot);
            const uint4 vA = *(const uint4*)(g + (size_t)sA * HID + h * 8);
            a0 += blo(vA.x); a1 += bhi(vA.x); a2 += blo(vA.y); a3 += bhi(vA.y);
            a4 += blo(vA.z); a5 += bhi(vA.z); a6 += blo(vA.w); a7 += bhi(vA.w);
        }
        // tail: shfl by ALL lanes, divergent load+add only
        int q = nfull * 8 + slot;
        int sA = __shfl(idx, q & 63);
        if (q < cnt) {
            const uint4 vA = *(const uint4*)(g + (size_t)sA * HID + h * 8);
            a0 += blo(vA.x); a1 += bhi(vA.x); a2 += blo(vA.y); a3 += bhi(vA.y);
            a4 += blo(vA.z); a5 += bhi(vA.z); a6 += blo(vA.w); a7 += bhi(vA.w);
        }
    }
    #pragma unroll
    for (int mask = 8; mask <= 32; mask <<= 1) {
        a0 += __shfl_xor(a0, mask); a1 += __shfl_xor(a1, mask);
        a2 += __shfl_xor(a2, mask); a3 += __shfl_xor(a3, mask);
        a4 += __shfl_xor(a4, mask); a5 += __shfl_xor(a5, mask);
        a6 += __shfl_xor(a6, mask); a7 += __shfl_xor(a7, mask);
    }
    // self-loop AFTER reduce
    {
        const uint4 gv = *(const uint4*)(g + (size_t)row * HID + h * 8);
        a0 += blo(gv.x); a1 += bhi(gv.x);
        a2 += blo(gv.y); a3 += bhi(gv.y);
        a4 += blo(gv.z); a5 += bhi(gv.z);
        a6 += blo(gv.w); a7 += bhi(gv.w);
    }
    float d = dis[row];
    float4 blo4 = *(const float4*)(b2 + h * 8);
    float4 bhi4 = *(const float4*)(b2 + h * 8 + 4);
    float4 wlo4 = *(const float4*)(Wl + h * 8);
    float4 whi4 = *(const float4*)(Wl + h * 8 + 4);
    float part = 0.f;
    float v;
    v = d * a0 + blo4.x; v = v > 0.f ? v : 0.f; part += v * wlo4.x;
    v = d * a1 + blo4.y; v = v > 0.f ? v : 0.f; part += v * wlo4.y;
    v = d * a2 + blo4.z; v = v > 0.f ? v : 0.f; part += v * wlo4.z;
    v = d * a3 + blo4.w; v = v > 0.f ? v : 0.f; part += v * wlo4.w;
    v = d * a4 + bhi4.x; v = v > 0.f ? v : 0.f; part += v * whi4.x;
    v = d * a5 + bhi4.y; v = v > 0.f ? v : 0.f; part += v * whi4.y;
    v = d * a6 + bhi4.z; v = v > 0.f ? v : 0.f; part += v * whi4.z;
    v = d * a7 + bhi4.w; v = v > 0.f ? v : 0.f; part += v * whi4.w;
    part += __shfl_xor(part, 1);
    part += __shfl_xor(part, 2);
    part += __shfl_xor(part, 4);
    if (lane == 0) out[row] = part + bl[0];
}

extern "C" void kernel_launch(void* const* d_in, const int* in_sizes, int n_in,
                              void* d_out, int out_size, void* d_ws, size_t ws_size,
                              hipStream_t stream) {
    const float* x  = (const float*)d_in[0];
    const int*   ei = (const int*)d_in[1];
    const float* W1 = (const float*)d_in[2];
    const float* b1 = (const float*)d_in[3];
    const float* W2 = (const float*)d_in[4];
    const float* b2 = (const float*)d_in[5];
    const float* Wl = (const float*)d_in[6];
    const float* bl = (const float*)d_in[7];
    float* out = (float*)d_out;

    const int N = in_sizes[0] / INC;    // 100000
    const int E = in_sizes[1] / 2;      // 3200000
    const int NB = (N + BINW - 1) / BINW;        // 391
    const int C  = (E + ECHUNK - 1) / ECHUNK;    // 391
    const int L  = NB * C;                        // 152881
    const int nScan = (L + SCAN_CHUNK - 1) / SCAN_CHUNK;  // 150 (<=512)

    char* ws = (char*)d_ws;
    size_t off = 0;
    auto alloc = [&](size_t bytes) { void* p = ws + off; off += (bytes + 255) / 256 * 256; return p; };
    int*   histT    = (int*)alloc((size_t)L * 4);     // scanned in place
    int*   blocksums= (int*)alloc(512 * 4);
    int*   blockoff = (int*)alloc(512 * 4);
    int*   rowptr   = (int*)alloc((size_t)(N + 1) * 4);
    float* dis      = (float*)alloc((size_t)N * 4);
    int*   csr      = (int*)alloc((size_t)E * 4);
    int*   bucket   = (int*)alloc((size_t)E * 4);
    bf16t* xs       = (bf16t*)alloc((size_t)N * XPAD * 2);   // 3.2 MB
    bf16t* a_bf     = (bf16t*)alloc((size_t)N * HID * 2);    // 12.8 MB
    bf16t* g2       = (bf16t*)alloc((size_t)N * HID * 2);    // 12.8 MB

    const int TPB = 256;
    const int* esrc = ei;
    const int* edst = ei + E;
    const int waveBlocks = ((size_t)N * 64 + TPB - 1) / TPB;

    // CSR build — zero global atomics; csrbuild also emits dis + xs
    k_hist<<<C, 512, 0, stream>>>(edst, E, C, NB, histT);
    k_scan1<<<nScan, TPB, 0, stream>>>(histT, L, histT, blocksums);
    k_scan2<<<1, 512, 0, stream>>>(blocksums, nScan, blockoff);
    k_scan3f<<<(L + TPB - 1) / TPB, TPB, 0, stream>>>(histT, blockoff, L);
    k_scatterbin<<<C, 512, 0, stream>>>(esrc, edst, E, C, NB, histT, bucket);
    k_csrbuild<<<NB, TPB, 0, stream>>>(histT, C, NB, E, bucket, csr, rowptr, dis, x, xs, N);

    // layer 1: x-space gather + W1 + relu -> a (bf16)
    k_agg1x<<<waveBlocks, TPB, 0, stream>>>(rowptr, csr, xs, dis, W1, b1, a_bf, N);

    // dense a@W2 -> g2 (bf16)
    k_xw2b<<<2048, TPB, 0, stream>>>(a_bf, W2, dis, g2, N);

    // layer 2: packed-gather aggregation + head
    k_agg2_head<<<waveBlocks, TPB, 0, stream>>>(rowptr, csr, g2, dis, b2, Wl, bl, out, N);
}